// Round 11
// baseline (2351.322 us; speedup 1.0000x reference)
//
#include <hip/hip_runtime.h>
#include <math.h>

#define DEV static __device__ __forceinline__

namespace {

constexpr int B = 8;
constexpr int N = 2048;     // points
constexpr int KNN = 32;     // neighbors
constexpr float BNEPS = 1e-5f;

DEV unsigned f2key(float f) {
  unsigned u = __float_as_uint(f);
  return (u & 0x80000000u) ? ~u : (u | 0x80000000u);  // monotone float->uint
}

DEV void atomicMaxFloat(float* addr, float val) {
  if (val >= 0.0f) atomicMax((int*)addr, __float_as_int(val));
  else atomicMin((unsigned int*)addr, (unsigned int)__float_as_int(val));
}

// ---------- radix top-32 select over 256 threads x NK register keys ----------
struct SelScratch {
  unsigned hist[256];
  int ss[257];
  int bin;
  int cnt;
};

template <int NK>
DEV unsigned long long radix_select32(const unsigned long long (&keys)[NK], SelScratch& s) {
  const int t = threadIdx.x;
  const int lane = t & 63, wave = t >> 6;
  unsigned long long prefix = 0; unsigned long long T = 0;
  int needed = KNN;
  bool done = false;
  for (int level = 0; level < 8 && !done; ++level) {
    int shift = 56 - 8 * level;
    s.hist[t] = 0;
    __syncthreads();
    unsigned long long maskhi = level ? (~0ull << (64 - 8 * level)) : 0ull;
    #pragma unroll
    for (int j = 0; j < NK; ++j) {
      if ((keys[j] & maskhi) == prefix)
        atomicAdd(&s.hist[(unsigned)(keys[j] >> shift) & 255u], 1u);
    }
    __syncthreads();
    if (wave == 0) {
      unsigned h0 = s.hist[4 * lane], h1 = s.hist[4 * lane + 1], h2 = s.hist[4 * lane + 2], h3 = s.hist[4 * lane + 3];
      unsigned s3 = h3, s2 = h2 + s3, s1 = h1 + s2, s0 = h0 + s1;
      unsigned suf = s0;
      #pragma unroll
      for (int off = 1; off < 64; off <<= 1) {
        unsigned v = __shfl_down(suf, off);
        if (lane + off < 64) suf += v;
      }
      unsigned above = suf - s0;
      s.ss[4 * lane] = (int)(s0 + above); s.ss[4 * lane + 1] = (int)(s1 + above);
      s.ss[4 * lane + 2] = (int)(s2 + above); s.ss[4 * lane + 3] = (int)(s3 + above);
      if (lane == 63) s.ss[256] = 0;
    }
    __syncthreads();
    if (s.ss[t] >= needed && s.ss[t + 1] < needed) s.bin = t;
    __syncthreads();
    int bin = s.bin;
    int hc = (int)s.hist[bin];
    needed -= s.ss[bin + 1];
    prefix |= ((unsigned long long)(unsigned)bin) << shift;
    if (needed == hc) { T = prefix; done = true; }
    __syncthreads();
  }
  return T;
}

template <int NK>
DEV void collect32(const unsigned long long (&keys)[NK], unsigned long long T, SelScratch& s,
                   int* __restrict__ out) {
  if (threadIdx.x == 0) s.cnt = 0;
  __syncthreads();
  #pragma unroll
  for (int j = 0; j < NK; ++j) {
    if (keys[j] >= T) {
      int pos = atomicAdd(&s.cnt, 1);
      out[pos] = (int)~(unsigned)keys[j];
    }
  }
  __syncthreads();
}

// ---------------- KNN 1 (C=3), exact f64 distances, radix select ----------------
__global__ __launch_bounds__(256) void knn1_kernel(const float* __restrict__ x, int* __restrict__ idx) {
  __shared__ SelScratch s;
  __shared__ double cc[3];
  int bn = blockIdx.x, b = bn >> 11, n = bn & (N - 1);
  int t = threadIdx.x;
  const float* xb = x + (size_t)b * 3 * N;
  if (t < 3) cc[t] = (double)xb[(size_t)t * N + n];
  __syncthreads();
  double cx = cc[0], cy = cc[1], cz = cc[2];
  unsigned long long keys[8];
  #pragma unroll
  for (int j = 0; j < 8; ++j) {
    int m = t + 256 * j;
    double dx = (double)xb[m] - cx, dy = (double)xb[N + m] - cy, dz = (double)xb[2 * N + m] - cz;
    double pd = -(dx * dx + dy * dy + dz * dz);
    keys[j] = ((unsigned long long)f2key((float)pd) << 32) | (unsigned)~m;
  }
  __syncthreads();
  unsigned long long T = radix_select32(keys, s);
  collect32(keys, T, s, idx + (size_t)bn * KNN);
}

// ---------------- EdgeConv 1 (6 -> 64): non-fma sequential-c, dot-then-bias ----------------
__global__ __launch_bounds__(256) void edge1_kernel(const float* __restrict__ x, const int* __restrict__ idx,
    const float* __restrict__ We1, const float* __restrict__ be1,
    float* __restrict__ emax, double* __restrict__ epart) {
  __shared__ float Ws[6][65];   // [c][o]
  __shared__ float fs[6][33];   // [c][k]
  __shared__ float es[64][33];  // [o][k]
  __shared__ int  is[KNN];
  int bn = blockIdx.x, b = bn >> 11, n = bn & (N - 1);
  int t = threadIdx.x;
  if (t < KNN) is[t] = idx[(size_t)bn * KNN + t];
  for (int e = t; e < 64 * 6; e += 256) Ws[e % 6][e / 6] = We1[e];  // We1[o][c]
  __syncthreads();
  const float* xb = x + (size_t)b * 3 * N;
  for (int e = t; e < 6 * KNN; e += 256) {
    int c = e >> 5, k = e & 31;
    int m = is[k];
    fs[c][k] = (c < 3) ? (xb[(size_t)c * N + m] - xb[(size_t)c * N + n]) : xb[(size_t)(c - 3) * N + n];
  }
  __syncthreads();
  int k = t & 31, orow = t >> 5;
  float acc[8];
  #pragma unroll
  for (int j = 0; j < 8; ++j) acc[j] = 0.0f;
  #pragma unroll
  for (int c = 0; c < 6; ++c) {
    float fv = fs[c][k];
    #pragma unroll
    for (int j = 0; j < 8; ++j) acc[j] = __fadd_rn(acc[j], __fmul_rn(Ws[c][orow * 8 + j], fv));
  }
  #pragma unroll
  for (int j = 0; j < 8; ++j) es[orow * 8 + j][k] = __fadd_rn(acc[j], be1[orow * 8 + j]);
  __syncthreads();
  if (t < 64) {
    double sum = 0, s2 = 0; float mx = -3.402823466e38f;
    #pragma unroll 8
    for (int kk = 0; kk < KNN; ++kk) {
      float v = es[t][kk]; double dv = (double)v;
      sum += dv; s2 = fma(dv, dv, s2); mx = fmaxf(mx, v);
    }
    emax[((size_t)b * 64 + t) * N + n] = mx;
    epart[(size_t)bn * 128 + t] = sum;
    epart[(size_t)bn * 128 + 64 + t] = s2;
  }
}

// reduce per-block edge partials (f64) -> per-channel mean / var (f32 outputs)
__global__ __launch_bounds__(256) void edge_stats_kernel(const double* __restrict__ epart, float* __restrict__ ems) {
  __shared__ double r1[256], r2[256];
  int o = blockIdx.x, t = threadIdx.x;
  double s = 0, s2 = 0;
  for (int i = t; i < B * N; i += 256) { s += epart[(size_t)i * 128 + o]; s2 += epart[(size_t)i * 128 + 64 + o]; }
  r1[t] = s; r2[t] = s2; __syncthreads();
  for (int st = 128; st > 0; st >>= 1) { if (t < st) { r1[t] += r1[t + st]; r2[t] += r2[t + st]; } __syncthreads(); }
  if (t == 0) {
    double cnt = (double)(B * N * KNN);
    double m = r1[0] / cnt, v = r2[0] / cnt - m * m;
    ems[o] = (float)m; ems[64 + o] = (float)v;
  }
}

// BN+ReLU finish; optionally also writes the [b][n][c] transposed copy
__global__ __launch_bounds__(256) void edge_finish_kernel(const float* __restrict__ emax, const float* __restrict__ ems,
                                                          float* __restrict__ f, float* __restrict__ ft) {
  size_t i = (size_t)blockIdx.x * 256 + threadIdx.x;  // B*64*N
  int c = (int)((i >> 11) & 63);
  float sd = sqrtf(ems[64 + c] + BNEPS);
  float v = (emax[i] - ems[c]) / sd;
  v = v > 0.f ? v : 0.f;
  f[i] = v;
  if (ft) {
    int n = (int)(i & (N - 1)); int b = (int)(i >> 17);
    ft[((size_t)b * N + n) * 64 + c] = v;
  }
}

__global__ __launch_bounds__(256) void xx2_kernel(const float* __restrict__ f1, double* __restrict__ xx2) {
  int i = blockIdx.x * 256 + threadIdx.x;  // B*N
  int b = i >> 11, n = i & (N - 1);
  const float* p = f1 + (size_t)b * 64 * N + n;
  double s = 0;
  #pragma unroll 16
  for (int c = 0; c < 64; ++c) { double v = (double)p[(size_t)c * N]; s = fma(v, v, s); }
  xx2[i] = s;
}

// ---------------- KNN 2 (C=64), f64 distances, 4 rows/block, radix select ----------------
__global__ __launch_bounds__(256) void knn2_kernel(const float* __restrict__ f1, const float* __restrict__ f1t,
                                                   const double* __restrict__ xx2, int* __restrict__ idx) {
  __shared__ SelScratch s;
  __shared__ double ctr[4][64];
  __shared__ unsigned long long stash[2][8][256];
  int bx = blockIdx.x, b = bx >> 9, n0 = (bx & 511) * 4;
  int t = threadIdx.x;
  { int i = t >> 6, c = t & 63; ctr[i][c] = (double)f1t[((size_t)b * N + n0 + i) * 64 + c]; }
  __syncthreads();
  const float* fb = f1 + (size_t)b * 64 * N;
  const double* xxb = xx2 + (size_t)b * N;
  double xxn0 = xxb[n0], xxn1 = xxb[n0 + 1], xxn2 = xxb[n0 + 2], xxn3 = xxb[n0 + 3];
  int mbase = t * 8;
  double xm[8];
  #pragma unroll
  for (int j = 0; j < 8; ++j) xm[j] = xxb[mbase + j];
  double a[4][8];
  #pragma unroll
  for (int i = 0; i < 4; ++i)
    #pragma unroll
    for (int j = 0; j < 8; ++j) a[i][j] = 0.0;
  #pragma unroll 4
  for (int c = 0; c < 64; ++c) {
    double w0 = ctr[0][c], w1 = ctr[1][c], w2 = ctr[2][c], w3 = ctr[3][c];
    float4 fA = *(const float4*)&fb[(size_t)c * N + mbase];
    float4 fB = *(const float4*)&fb[(size_t)c * N + mbase + 4];
    float fv[8] = {fA.x, fA.y, fA.z, fA.w, fB.x, fB.y, fB.z, fB.w};
    #pragma unroll
    for (int j = 0; j < 8; ++j) {
      double v = (double)fv[j];
      a[0][j] = fma(v, w0, a[0][j]);
      a[1][j] = fma(v, w1, a[1][j]);
      a[2][j] = fma(v, w2, a[2][j]);
      a[3][j] = fma(v, w3, a[3][j]);
    }
  }
  unsigned long long k0[8], k1[8];
  #pragma unroll
  for (int j = 0; j < 8; ++j) {
    unsigned long long lo = (unsigned)~(mbase + j);
    k0[j] = ((unsigned long long)f2key((float)(-xxn0 + 2.0 * a[0][j] - xm[j])) << 32) | lo;
    k1[j] = ((unsigned long long)f2key((float)(-xxn1 + 2.0 * a[1][j] - xm[j])) << 32) | lo;
    stash[0][j][t] = ((unsigned long long)f2key((float)(-xxn2 + 2.0 * a[2][j] - xm[j])) << 32) | lo;
    stash[1][j][t] = ((unsigned long long)f2key((float)(-xxn3 + 2.0 * a[3][j] - xm[j])) << 32) | lo;
  }
  __syncthreads();
  unsigned long long T;
  T = radix_select32(k0, s); collect32(k0, T, s, idx + ((size_t)b * N + n0 + 0) * KNN);
  T = radix_select32(k1, s); collect32(k1, T, s, idx + ((size_t)b * N + n0 + 1) * KNN);
  unsigned long long kk[8];
  #pragma unroll
  for (int j = 0; j < 8; ++j) kk[j] = stash[0][j][t];
  T = radix_select32(kk, s); collect32(kk, T, s, idx + ((size_t)b * N + n0 + 2) * KNN);
  #pragma unroll
  for (int j = 0; j < 8; ++j) kk[j] = stash[1][j][t];
  T = radix_select32(kk, s); collect32(kk, T, s, idx + ((size_t)b * N + n0 + 3) * KNN);
}

// ---------------- EdgeConv 2 (128 -> 64), 4 points/block, register tile 4o x 8k ----------------
__global__ __launch_bounds__(256) void edge2_kernel(const float* __restrict__ f1t, const int* __restrict__ idx,
    const float* __restrict__ We2, const float* __restrict__ be2,
    float* __restrict__ emax, double* __restrict__ epart) {
  __shared__ __align__(16) float smem[8448];
  __shared__ int is[4][32];
  float* Wsb = smem;                // [c][o] stride 68
  float* fsb = smem + 2176;         // [p][c][k] stride 36 in k
  int bx = blockIdx.x;  // B * 512
  int b = bx >> 9, n0 = (bx & 511) * 4;
  int t = threadIdx.x;
  if (t < 128) is[t >> 5][t & 31] = idx[((size_t)b * N + n0 + (t >> 5)) * KNN + (t & 31)];
  int o4 = t & 15, kq = (t >> 4) & 3, p = t >> 6;
  float acc[4][8];
  #pragma unroll
  for (int i = 0; i < 4; ++i)
    #pragma unroll
    for (int j = 0; j < 8; ++j) acc[i][j] = 0.f;
  const float* fbt = f1t + (size_t)b * N * 64;
  for (int cc = 0; cc < 4; ++cc) {
    int c0 = cc * 32;
    __syncthreads();
    for (int e = t; e < 2048; e += 256) { int o = e >> 5, c = e & 31; Wsb[c * 68 + o] = We2[(size_t)o * 128 + c0 + c]; }
    for (int e = t; e < 4096; e += 256) {
      int c = e & 31, kk = (e >> 5) & 31, pp = e >> 10;
      int m = is[pp][kk];
      int cg = c0 + c;
      float v = (cg < 64) ? (fbt[(size_t)m * 64 + cg] - fbt[(size_t)(n0 + pp) * 64 + cg])
                          : fbt[(size_t)(n0 + pp) * 64 + (cg - 64)];
      fsb[(pp * 32 + c) * 36 + kk] = v;
    }
    __syncthreads();
    #pragma unroll 4
    for (int c = 0; c < 32; ++c) {
      float4 w4 = *(const float4*)&Wsb[c * 68 + o4 * 4];
      float4 fa = *(const float4*)&fsb[(p * 32 + c) * 36 + kq * 8];
      float4 fb = *(const float4*)&fsb[(p * 32 + c) * 36 + kq * 8 + 4];
      float wv[4]; *(float4*)wv = w4;
      float fv[8]; *(float4*)fv = fa; *(float4*)(fv + 4) = fb;
      #pragma unroll
      for (int i = 0; i < 4; ++i)
        #pragma unroll
        for (int j = 0; j < 8; ++j) acc[i][j] = fmaf(wv[i], fv[j], acc[i][j]);
    }
  }
  __syncthreads();  // before overwriting phase-A LDS with es
  {
    float bv[4]; *(float4*)bv = *(const float4*)&be2[o4 * 4];
    #pragma unroll
    for (int j = 0; j < 8; ++j) {
      int k = kq * 8 + j;
      float4 v4 = make_float4(acc[0][j] + bv[0], acc[1][j] + bv[1], acc[2][j] + bv[2], acc[3][j] + bv[3]);
      *(float4*)&smem[k * 264 + p * 64 + o4 * 4] = v4;
    }
  }
  __syncthreads();
  {
    int pp = t >> 6, o = t & 63;
    double sum = 0, s2 = 0; float mx = -3.402823466e38f;
    #pragma unroll 8
    for (int kk = 0; kk < KNN; ++kk) {
      float v = smem[kk * 264 + pp * 64 + o]; double dv = (double)v;
      sum += dv; s2 = fma(dv, dv, s2); mx = fmaxf(mx, v);
    }
    int n = n0 + pp;
    emax[((size_t)b * 64 + o) * N + n] = mx;
    epart[((size_t)b * N + n) * 128 + o] = sum;
    epart[((size_t)b * N + n) * 128 + 64 + o] = s2;
  }
}

__global__ __launch_bounds__(256) void concat_feat_kernel(const float* __restrict__ f1, const float* __restrict__ f2,
                                                          float* __restrict__ feat) {
  size_t i = (size_t)blockIdx.x * 256 + threadIdx.x;  // B*128*N
  int n = (int)(i & (N - 1)); int c = (int)((i >> 11) & 127); int b = (int)(i >> 18);
  feat[i] = (c < 64) ? f1[((size_t)b * 64 + c) * N + n] : f2[((size_t)b * 64 + (c - 64)) * N + n];
}

// ---------------- SA layer ----------------
// Cout=64 (32 q + 32 k); o-tile 64, n-tile 64; float4 LDS microkernel
__global__ __launch_bounds__(256) void sa_qk_kernel(const float* __restrict__ xs, int xs_bstride, int xs_coff,
    const float* __restrict__ Wq, const float* __restrict__ Wk,
    float* __restrict__ xq, float* __restrict__ xk) {
  __shared__ __align__(16) float Ws[32][68];  // [c][o]
  __shared__ __align__(16) float vs[32][68];  // [c][n]
  int bx = blockIdx.x, b = bx >> 5, n0 = (bx & 31) * 64;
  int t = threadIdx.x;
  int tc = t >> 4, tm = t & 15;
  float acc[4][4];
  #pragma unroll
  for (int i = 0; i < 4; ++i)
    #pragma unroll
    for (int j = 0; j < 4; ++j) acc[i][j] = 0.f;
  for (int cc = 0; cc < 4; ++cc) {
    int c0 = cc * 32;
    __syncthreads();
    // staging decomposition: o_low=e&15, cq=(e>>4)&7, o_hi=e>>7 -> 2-way LDS bank (free)
    for (int e = t; e < 512; e += 256) {
      int o = (e & 15) | ((e >> 7) << 4), cq = (e >> 4) & 7;
      float4 w4 = (o < 32) ? *(const float4*)&Wq[o * 128 + c0 + cq * 4]
                           : *(const float4*)&Wk[(o - 32) * 128 + c0 + cq * 4];
      Ws[cq * 4 + 0][o] = w4.x; Ws[cq * 4 + 1][o] = w4.y; Ws[cq * 4 + 2][o] = w4.z; Ws[cq * 4 + 3][o] = w4.w;
    }
    for (int e = t; e < 512; e += 256) {
      int c = e >> 4, nq = e & 15;
      *(float4*)&vs[c][nq * 4] =
          *(const float4*)&xs[(size_t)b * xs_bstride + (size_t)(xs_coff + c0 + c) * N + n0 + nq * 4];
    }
    __syncthreads();
    #pragma unroll 4
    for (int c = 0; c < 32; ++c) {
      float4 w4 = *(const float4*)&Ws[c][tc * 4];
      float4 v4 = *(const float4*)&vs[c][tm * 4];
      float wv[4] = {w4.x, w4.y, w4.z, w4.w};
      float vv[4] = {v4.x, v4.y, v4.z, v4.w};
      #pragma unroll
      for (int i = 0; i < 4; ++i)
        #pragma unroll
        for (int j = 0; j < 4; ++j) acc[i][j] = fmaf(wv[i], vv[j], acc[i][j]);
    }
  }
  #pragma unroll
  for (int i = 0; i < 4; ++i) {
    int o2 = tc * 4 + i;
    if (o2 < 32) {
      #pragma unroll
      for (int j = 0; j < 4; ++j) {
        int n = n0 + tm * 4 + j;
        xq[((size_t)b * N + n) * 32 + o2] = acc[i][j];
      }
    } else {
      float4 o4 = make_float4(acc[i][0], acc[i][1], acc[i][2], acc[i][3]);
      *(float4*)&xk[((size_t)b * 32 + (o2 - 32)) * N + n0 + tm * 4] = o4;
    }
  }
}

// GEMM-style row softmax stats: 128 rows x 512-m chunk per block; online (max,sum)
// epilogue per tile, fully register-resident; 16-lane shfl merge; 4 partials/row.
// grid: rowtile(16) x mchunk(4) x b(8) = 512 blocks
__global__ __launch_bounds__(256) void sa_rowstats_kernel(const float* __restrict__ xq, const float* __restrict__ xk,
    float* __restrict__ rowpart) {
  __shared__ __align__(16) float Qs[32][132];  // [q][row]
  __shared__ __align__(16) float Ks[32][68];   // [q][m]
  int bx = blockIdx.x;
  int rt = bx & 15, mc = (bx >> 4) & 3, b = bx >> 6;
  int n0 = rt * 128, m0 = mc * 512;
  int t = threadIdx.x, tc = t >> 4, tm = t & 15;
  // stage Q (128 rows x 32 q), transposed to [q][row]; conflict-free decomposition
  for (int e = t; e < 1024; e += 256) {
    int r = (e & 15) | ((e >> 7) << 4), q4 = (e >> 4) & 7;
    float4 v = *(const float4*)&xq[((size_t)b * N + n0 + r) * 32 + q4 * 4];
    Qs[q4 * 4 + 0][r] = v.x; Qs[q4 * 4 + 1][r] = v.y; Qs[q4 * 4 + 2][r] = v.z; Qs[q4 * 4 + 3][r] = v.w;
  }
  float rm8[8], rs8[8];
  #pragma unroll
  for (int i = 0; i < 8; ++i) { rm8[i] = -3.402823466e38f; rs8[i] = 0.f; }
  for (int mt = 0; mt < 8; ++mt) {
    int mbase = m0 + mt * 64;
    __syncthreads();
    for (int e = t; e < 512; e += 256) {
      int q = e >> 4, m4 = e & 15;
      *(float4*)&Ks[q][m4 * 4] = *(const float4*)&xk[((size_t)b * 32 + q) * N + mbase + m4 * 4];
    }
    __syncthreads();
    float acc[8][4];
    #pragma unroll
    for (int jc = 0; jc < 8; ++jc)
      #pragma unroll
      for (int jm = 0; jm < 4; ++jm) acc[jc][jm] = 0.f;
    #pragma unroll 4
    for (int c = 0; c < 32; ++c) {
      float4 w0 = *(const float4*)&Qs[c][tc * 4];
      float4 w1 = *(const float4*)&Qs[c][tc * 4 + 64];
      float4 k4 = *(const float4*)&Ks[c][tm * 4];
      float wv[8] = {w0.x, w0.y, w0.z, w0.w, w1.x, w1.y, w1.z, w1.w};
      float kv[4] = {k4.x, k4.y, k4.z, k4.w};
      #pragma unroll
      for (int jc = 0; jc < 8; ++jc)
        #pragma unroll
        for (int jm = 0; jm < 4; ++jm) acc[jc][jm] = fmaf(wv[jc], kv[jm], acc[jc][jm]);
    }
    // online update (compile-time indices only)
    #pragma unroll
    for (int jc = 0; jc < 8; ++jc) {
      #pragma unroll
      for (int jm = 0; jm < 4; ++jm) {
        float e2 = acc[jc][jm];
        if (e2 > rm8[jc]) { rs8[jc] = rs8[jc] * __expf(rm8[jc] - e2) + 1.0f; rm8[jc] = e2; }
        else rs8[jc] += __expf(e2 - rm8[jc]);
      }
    }
  }
  // merge across the 16 tm-lanes (within-wave 16-lane groups)
  #pragma unroll
  for (int jc = 0; jc < 8; ++jc) {
    float M = rm8[jc], S = rs8[jc];
    #pragma unroll
    for (int off = 1; off < 16; off <<= 1) {
      float M2 = __shfl_xor(M, off), S2 = __shfl_xor(S, off);
      float mm = fmaxf(M, M2);
      S = S * __expf(M - mm) + S2 * __expf(M2 - mm);
      M = mm;
    }
    if (tm == 0) {
      int r = n0 + tc * 4 + (jc & 3) + (jc >> 2) * 64;
      size_t o = ((size_t)mc * (B * N) + (size_t)b * N + r) * 2;
      rowpart[o] = M; rowpart[o + 1] = S;
    }
  }
}

__global__ void rowstats_merge_kernel(const float* __restrict__ rowpart,
                                      float* __restrict__ rowmax, float* __restrict__ rowsum) {
  int i = blockIdx.x * 256 + threadIdx.x;  // B*N
  float M = rowpart[(size_t)i * 2], S = rowpart[(size_t)i * 2 + 1];
  #pragma unroll
  for (int mc = 1; mc < 4; ++mc) {
    size_t o = ((size_t)mc * (B * N) + i) * 2;
    float M2 = rowpart[o], S2 = rowpart[o + 1];
    float mm = fmaxf(M, M2);
    S = S * __expf(M - mm) + S2 * __expf(M2 - mm);
    M = mm;
  }
  rowmax[i] = M; rowsum[i] = S;
}

// Y = xs @ P (P recomputed tile-wise) over an n-chunk; partial Y + colsum per chunk.
// grid: b(8) x mtile(32) x g(4). K-column in registers; XOR-swizzled vs staging.
__global__ __launch_bounds__(256) void sa_attny_kernel(const float* __restrict__ xs, int xs_bstride, int xs_coff,
    const float* __restrict__ xq, const float* __restrict__ xk,
    const float* __restrict__ rowmax, const float* __restrict__ rowsum,
    float* __restrict__ Yp, float* __restrict__ cspart) {
  __shared__ __align__(16) float qs[64][36];   // [n][q]
  __shared__ float rmv[64], rsv[64];
  __shared__ __align__(16) float Ps[64][68];   // [n][m]
  __shared__ __align__(16) float vs[64][132];  // [n][SW(c)] (c = 0..127)
  __shared__ float csr[4][64];
  int bx = blockIdx.x;
  int g = bx & 3, m0 = ((bx >> 2) & 31) * 64, b = bx >> 7;
  int t = threadIdx.x;
  int tc = t >> 4, tm = t & 15;
  int tmm = t & 63, tns = t >> 6;
  float kreg[32];
  #pragma unroll
  for (int q = 0; q < 32; ++q) kreg[q] = xk[((size_t)b * 32 + q) * N + m0 + tmm];
  float acc[2][4][4];
  #pragma unroll
  for (int h = 0; h < 2; ++h)
    #pragma unroll
    for (int i = 0; i < 4; ++i)
      #pragma unroll
      for (int j = 0; j < 4; ++j) acc[h][i][j] = 0.f;
  float cs = 0.f;
  const float* xsb = xs + (size_t)b * xs_bstride + (size_t)xs_coff * N;
  for (int nt = g * 8; nt < g * 8 + 8; ++nt) {
    int n0 = nt * 64;
    __syncthreads();
    for (int e = t; e < 512; e += 256) {
      int nn = e >> 3, qq = e & 7;
      *(float4*)&qs[nn][qq * 4] = *(const float4*)&xq[((size_t)b * N + n0 + nn) * 32 + qq * 4];
    }
    if (t < 64) { rmv[t] = rowmax[(size_t)b * N + n0 + t]; rsv[t] = 1.0f / rowsum[(size_t)b * N + n0 + t]; }
    for (int e = t; e < 128 * 64; e += 256) {
      int c = e >> 6, nn = e & 63;
      int M = (nn & 3) | (((nn >> 3) & 7) << 2);
      vs[nn][c ^ M] = xsb[(size_t)c * N + n0 + nn];
    }
    __syncthreads();
    float cp = 0.f;
    #pragma unroll 1
    for (int jj = 0; jj < 16; ++jj) {
      int nn = tns * 16 + jj;
      float ea = 0, eb = 0, ec = 0, ed = 0;
      #pragma unroll
      for (int q4 = 0; q4 < 8; ++q4) {
        float4 qv = *(const float4*)&qs[nn][q4 * 4];
        ea = fmaf(qv.x, kreg[4 * q4 + 0], ea);
        eb = fmaf(qv.y, kreg[4 * q4 + 1], eb);
        ec = fmaf(qv.z, kreg[4 * q4 + 2], ec);
        ed = fmaf(qv.w, kreg[4 * q4 + 3], ed);
      }
      float e2 = (ea + eb) + (ec + ed);
      float p = __expf(e2 - rmv[nn]) * rsv[nn];
      Ps[nn][tmm] = p; cp += p;
    }
    csr[tns][tmm] = cp;
    __syncthreads();
    if (t < 64) cs += csr[0][t] + csr[1][t] + csr[2][t] + csr[3][t];
    #pragma unroll 1
    for (int nn8 = 0; nn8 < 8; ++nn8) {
      int s2x = nn8 << 2;
      int b0 = (tc * 4) ^ s2x;
      #pragma unroll
      for (int kk = 0; kk < 8; ++kk) {
        int nn = nn8 * 8 + kk;
        const int k = kk & 3;
        float4 pa = *(const float4*)&Ps[nn][tm * 4];
        float4 q0 = *(const float4*)&vs[nn][b0];
        float4 q1 = *(const float4*)&vs[nn][64 + b0];
        float pv[4]; *(float4*)pv = pa;
        float xr0[4]; *(float4*)xr0 = q0;
        float xr1[4]; *(float4*)xr1 = q1;
        float xv0[4] = {xr0[0 ^ k], xr0[1 ^ k], xr0[2 ^ k], xr0[3 ^ k]};
        float xv1[4] = {xr1[0 ^ k], xr1[1 ^ k], xr1[2 ^ k], xr1[3 ^ k]};
        #pragma unroll
        for (int i = 0; i < 4; ++i)
          #pragma unroll
          for (int jm = 0; jm < 4; ++jm) {
            acc[0][i][jm] = fmaf(xv0[i], pv[jm], acc[0][i][jm]);
            acc[1][i][jm] = fmaf(xv1[i], pv[jm], acc[1][i][jm]);
          }
      }
    }
  }
  #pragma unroll
  for (int h = 0; h < 2; ++h)
    #pragma unroll
    for (int i = 0; i < 4; ++i) {
      float4 o4 = make_float4(acc[h][i][0], acc[h][i][1], acc[h][i][2], acc[h][i][3]);
      *(float4*)&Yp[(((size_t)g * B + b) * 128 + h * 64 + tc * 4 + i) * N + m0 + tm * 4] = o4;
    }
  if (t < 64) cspart[((size_t)g * B + b) * N + m0 + t] = cs;
}

__global__ __launch_bounds__(256) void sa_wt_kernel(const float* __restrict__ xs, int xs_bstride, int xs_coff,
    const float* __restrict__ Yp, const float* __restrict__ cspart,
    const float* __restrict__ Wt, const float* __restrict__ bt,
    float* __restrict__ tpre) {
  __shared__ __align__(16) float Ws[32][132];
  __shared__ __align__(16) float vs[32][68];
  __shared__ __align__(16) float inv[64];
  int bx = blockIdx.x, b = bx >> 5, n0 = (bx & 31) * 64;
  int t = threadIdx.x;
  if (t < 64) {
    float s = 0;
    #pragma unroll
    for (int g = 0; g < 4; ++g) s += cspart[((size_t)g * B + b) * N + n0 + t];
    inv[t] = 1.0f / (1e-6f + s);
  }
  int tc = t >> 4, tm = t & 15;
  float acc[8][4];
  #pragma unroll
  for (int jc = 0; jc < 8; ++jc)
    #pragma unroll
    for (int jm = 0; jm < 4; ++jm) acc[jc][jm] = 0.f;
  for (int cc = 0; cc < 4; ++cc) {
    int c0 = cc * 32;
    __syncthreads();
    for (int e = t; e < 1024; e += 256) {
      int o = (e & 15) | ((e >> 7) << 4), cq = (e >> 4) & 7;
      float4 w4 = *(const float4*)&Wt[o * 128 + c0 + cq * 4];
      Ws[cq * 4 + 0][o] = w4.x; Ws[cq * 4 + 1][o] = w4.y; Ws[cq * 4 + 2][o] = w4.z; Ws[cq * 4 + 3][o] = w4.w;
    }
    for (int e = t; e < 512; e += 256) {
      int c = e >> 4, nq = e & 15;
      float4 xv = *(const float4*)&xs[(size_t)b * xs_bstride + (size_t)(xs_coff + c0 + c) * N + n0 + nq * 4];
      float4 ys = make_float4(0.f, 0.f, 0.f, 0.f);
      #pragma unroll
      for (int g = 0; g < 4; ++g) {
        float4 yv = *(const float4*)&Yp[(((size_t)g * B + b) * 128 + c0 + c) * N + n0 + nq * 4];
        ys.x += yv.x; ys.y += yv.y; ys.z += yv.z; ys.w += yv.w;
      }
      float4 iv = *(const float4*)&inv[nq * 4];
      float4 r = make_float4(xv.x - ys.x * iv.x, xv.y - ys.y * iv.y, xv.z - ys.z * iv.z, xv.w - ys.w * iv.w);
      *(float4*)&vs[c][nq * 4] = r;
    }
    __syncthreads();
    #pragma unroll 4
    for (int c = 0; c < 32; ++c) {
      float4 w0 = *(const float4*)&Ws[c][tc * 4];
      float4 w1 = *(const float4*)&Ws[c][tc * 4 + 64];
      float4 v4 = *(const float4*)&vs[c][tm * 4];
      float wv[8] = {w0.x, w0.y, w0.z, w0.w, w1.x, w1.y, w1.z, w1.w};
      float vv[4] = {v4.x, v4.y, v4.z, v4.w};
      #pragma unroll
      for (int jc = 0; jc < 8; ++jc)
        #pragma unroll
        for (int jm = 0; jm < 4; ++jm) acc[jc][jm] = fmaf(wv[jc], vv[jm], acc[jc][jm]);
    }
  }
  #pragma unroll
  for (int jc = 0; jc < 8; ++jc) {
    int o2 = tc * 4 + (jc & 3) + (jc >> 2) * 64;
    float bias = bt[o2];
    float4 o4 = make_float4(acc[jc][0] + bias, acc[jc][1] + bias, acc[jc][2] + bias, acc[jc][3] + bias);
    *(float4*)&tpre[((size_t)b * 128 + o2) * N + n0 + tm * 4] = o4;
  }
}

// per-channel mean/var over (B,N), f64 accumulation
__global__ __launch_bounds__(256) void chanstats_kernel(const float* __restrict__ x, float* __restrict__ ms, int C) {
  __shared__ double r1[256], r2[256];
  int c = blockIdx.x, t = threadIdx.x;
  double s = 0, s2 = 0;
  for (int i = t; i < B * N; i += 256) {
    int b = i >> 11, n = i & (N - 1);
    double v = (double)x[((size_t)b * C + c) * N + n];
    s += v; s2 = fma(v, v, s2);
  }
  r1[t] = s; r2[t] = s2; __syncthreads();
  for (int st = 128; st > 0; st >>= 1) { if (t < st) { r1[t] += r1[t + st]; r2[t] += r2[t + st]; } __syncthreads(); }
  if (t == 0) {
    double cnt = (double)(B * N);
    double m = r1[0] / cnt, v = r2[0] / cnt - m * m;
    ms[c] = (float)m; ms[C + c] = (float)v;
  }
}

__global__ __launch_bounds__(256) void sa_out_kernel(const float* __restrict__ tpre, const float* __restrict__ ms,
    const float* __restrict__ xs, int xs_bstride, int xs_coff, float* __restrict__ cat, int lay) {
  size_t i = (size_t)blockIdx.x * 256 + threadIdx.x;  // B*128*N
  int n = (int)(i & (N - 1)); int c = (int)((i >> 11) & 127); int b = (int)(i >> 18);
  float sd = sqrtf(ms[128 + c] + BNEPS);
  float v = (tpre[i] - ms[c]) / sd;
  v = v > 0.f ? v : 0.f;
  float xv = xs[(size_t)b * xs_bstride + (size_t)(xs_coff + c) * N + n];
  cat[((size_t)b * 512 + lay * 128 + c) * N + n] = xv + v;
}

// fuse: Wf@cat+bf -> 8x8 register tile; stats epilogue fully in registers
// grid: b(8) x otile(8) x ntile(16) = 1024; o,n half-split {ty*4+j} U {64+ty*4+j}
__global__ __launch_bounds__(256) void fuse_kernel(const float* __restrict__ cat, const float* __restrict__ Wf,
    const float* __restrict__ bf, float* __restrict__ fps, float* __restrict__ fps2, float* __restrict__ premax) {
  __shared__ __align__(16) float Ws[32][132];
  __shared__ __align__(16) float vs[32][132];
  int bx = blockIdx.x;
  int b = bx >> 7, o0 = ((bx >> 4) & 7) * 128, ntile = bx & 15, n0 = ntile * 128;
  int part = b * 16 + ntile;  // [0,128)
  int t = threadIdx.x, ty = t >> 4, tx = t & 15;
  float acc[8][8];
  #pragma unroll
  for (int jo = 0; jo < 8; ++jo)
    #pragma unroll
    for (int ji = 0; ji < 8; ++ji) acc[jo][ji] = 0.f;
  for (int cc = 0; cc < 16; ++cc) {
    int c0 = cc * 32;
    __syncthreads();
    for (int e = t; e < 1024; e += 256) {
      int o = (e & 15) | ((e >> 7) << 4), cq = (e >> 4) & 7;
      float4 w4 = *(const float4*)&Wf[(size_t)(o0 + o) * 512 + c0 + cq * 4];
      Ws[cq * 4 + 0][o] = w4.x; Ws[cq * 4 + 1][o] = w4.y; Ws[cq * 4 + 2][o] = w4.z; Ws[cq * 4 + 3][o] = w4.w;
    }
    for (int e = t; e < 1024; e += 256) {
      int c = e >> 5, nq = e & 31;
      *(float4*)&vs[c][nq * 4] = *(const float4*)&cat[((size_t)b * 512 + c0 + c) * N + n0 + nq * 4];
    }
    __syncthreads();
    #pragma unroll 4
    for (int c = 0; c < 32; ++c) {
      float4 w0 = *(const float4*)&Ws[c][ty * 4];
      float4 w1 = *(const float4*)&Ws[c][64 + ty * 4];
      float4 v0 = *(const float4*)&vs[c][tx * 4];
      float4 v1 = *(const float4*)&vs[c][64 + tx * 4];
      float wv[8] = {w0.x, w0.y, w0.z, w0.w, w1.x, w1.y, w1.z, w1.w};
      float vv[8] = {v0.x, v0.y, v0.z, v0.w, v1.x, v1.y, v1.z, v1.w};
      #pragma unroll
      for (int jo = 0; jo < 8; ++jo)
        #pragma unroll
        for (int ji = 0; ji < 8; ++ji) acc[jo][ji] = fmaf(wv[jo], vv[ji], acc[jo][ji]);
    }
  }
  // epilogue: bias + per-o (sum, sumsq, max) in registers; 16-lane tx reduce
  #pragma unroll
  for (int jo = 0; jo < 8; ++jo) {
    int o = ty * 4 + (jo & 3) + (jo >> 2) * 64;  // local o in [0,128)
    float bias = bf[o0 + o];
    double s = 0, s2 = 0; float mx = -3.402823466e38f;
    #pragma unroll
    for (int ji = 0; ji < 8; ++ji) {
      float v = acc[jo][ji] + bias;
      double dv = (double)v;
      s += dv; s2 = fma(dv, dv, s2); mx = fmaxf(mx, v);
    }
    #pragma unroll
    for (int off = 1; off < 16; off <<= 1) {
      s += __shfl_xor(s, off);
      s2 += __shfl_xor(s2, off);
      mx = fmaxf(mx, __shfl_xor(mx, off));
    }
    if (tx == 0) {
      fps[(size_t)(o0 + o) * 128 + part] = (float)s;
      fps2[(size_t)(o0 + o) * 128 + part] = (float)s2;
      atomicMaxFloat(&premax[(size_t)b * 1024 + o0 + o], mx);
    }
  }
}

__global__ __launch_bounds__(128) void fuse_stats_kernel(const float* __restrict__ fps, const float* __restrict__ fps2,
                                                         float* __restrict__ ms) {
  __shared__ double r1[128], r2[128];
  int o = blockIdx.x, t = threadIdx.x;
  r1[t] = (double)fps[(size_t)o * 128 + t];
  r2[t] = (double)fps2[(size_t)o * 128 + t];
  __syncthreads();
  for (int st = 64; st > 0; st >>= 1) { if (t < st) { r1[t] += r1[t + st]; r2[t] += r2[t + st]; } __syncthreads(); }
  if (t == 0) {
    double cnt = (double)(B * N);
    double m = r1[0] / cnt, v = r2[0] / cnt - m * m;
    ms[o] = (float)m; ms[1024 + o] = (float)v;
  }
}

__global__ void g_kernel(const float* __restrict__ premax, const float* __restrict__ ms, float* __restrict__ g) {
  int i = blockIdx.x * 256 + threadIdx.x;  // B*1024
  int o = i & 1023;
  float sd = sqrtf(ms[1024 + o] + BNEPS);
  float v = (premax[i] - ms[o]) / sd;
  g[i] = v > 0.f ? v : 0.f;
}

__global__ __launch_bounds__(256) void gproj_kernel(const float* __restrict__ Wc1, const float* __restrict__ g,
                                                    float* __restrict__ gproj) {
  int i = blockIdx.x * 256 + threadIdx.x;  // B*512
  int b = i >> 9, o = i & 511;
  const float* gb = g + (size_t)b * 1024;
  const float* wr = Wc1 + (size_t)o * 1536;
  float s = 0;
  #pragma unroll 8
  for (int c = 0; c < 1024; ++c) s = fmaf(wr[c], gb[c], s);
  gproj[i] = s;
}

// 8x8 register-tile GEMM: o-tile 128, n-tile 128; o,n half-split like fuse
// grid: b x (Cout/128) x (N/128)
__global__ __launch_bounds__(256) void mlp_gemm_kernel(const float* __restrict__ in, int Cin,
    const float* __restrict__ W, int wstride, int wcoff,
    const float* __restrict__ bias, const float* __restrict__ extra, int Cout,
    float* __restrict__ out) {
  __shared__ __align__(16) float Ws[32][132];
  __shared__ __align__(16) float vs[32][132];
  int otiles = Cout >> 7;
  int bx = blockIdx.x;
  int b = bx / (otiles * 16); int rem = bx % (otiles * 16);
  int o0 = (rem >> 4) * 128, n0 = (rem & 15) * 128;
  int t = threadIdx.x, ty = t >> 4, tx = t & 15;
  float acc[8][8];
  #pragma unroll
  for (int jo = 0; jo < 8; ++jo)
    #pragma unroll
    for (int ji = 0; ji < 8; ++ji) acc[jo][ji] = 0.f;
  for (int c0 = 0; c0 < Cin; c0 += 32) {
    __syncthreads();
    for (int e = t; e < 1024; e += 256) {
      int o = (e & 15) | ((e >> 7) << 4), cq = (e >> 4) & 7;
      float4 w4 = *(const float4*)&W[(size_t)(o0 + o) * wstride + wcoff + c0 + cq * 4];
      Ws[cq * 4 + 0][o] = w4.x; Ws[cq * 4 + 1][o] = w4.y; Ws[cq * 4 + 2][o] = w4.z; Ws[cq * 4 + 3][o] = w4.w;
    }
    for (int e = t; e < 1024; e += 256) {
      int c = e >> 5, nq = e & 31;
      *(float4*)&vs[c][nq * 4] = *(const float4*)&in[((size_t)b * Cin + c0 + c) * N + n0 + nq * 4];
    }
    __syncthreads();
    #pragma unroll 4
    for (int c = 0; c < 32; ++c) {
      float4 w0 = *(const float4*)&Ws[c][ty * 4];
      float4 w1 = *(const float4*)&Ws[c][64 + ty * 4];
      float4 v0 = *(const float4*)&vs[c][tx * 4];
      float4 v1 = *(const float4*)&vs[c][64 + tx * 4];
      float wv[8] = {w0.x, w0.y, w0.z, w0.w, w1.x, w1.y, w1.z, w1.w};
      float vv[8] = {v0.x, v0.y, v0.z, v0.w, v1.x, v1.y, v1.z, v1.w};
      #pragma unroll
      for (int jo = 0; jo < 8; ++jo)
        #pragma unroll
        for (int ji = 0; ji < 8; ++ji) acc[jo][ji] = fmaf(wv[jo], vv[ji], acc[jo][ji]);
    }
  }
  #pragma unroll
  for (int jo = 0; jo < 8; ++jo) {
    int o2 = o0 + ty * 4 + (jo & 3) + (jo >> 2) * 64;
    float add = bias[o2] + (extra ? extra[(size_t)b * Cout + o2] : 0.f);
    float4 a0 = make_float4(acc[jo][0] + add, acc[jo][1] + add, acc[jo][2] + add, acc[jo][3] + add);
    float4 a1 = make_float4(acc[jo][4] + add, acc[jo][5] + add, acc[jo][6] + add, acc[jo][7] + add);
    *(float4*)&out[((size_t)b * Cout + o2) * N + n0 + tx * 4] = a0;
    *(float4*)&out[((size_t)b * Cout + o2) * N + n0 + 64 + tx * 4] = a1;
  }
}

__global__ void bnrelu_inplace_kernel(float* __restrict__ x, const float* __restrict__ ms, int C) {
  size_t i = (size_t)blockIdx.x * 256 + threadIdx.x;  // B*C*N
  int c = (int)((i >> 11) & (C - 1));
  float sd = sqrtf(ms[C + c] + BNEPS);
  float v = (x[i] - ms[c]) / sd;
  x[i] = v > 0.f ? v : 0.f;
}

__global__ __launch_bounds__(256) void wc3_kernel(const float* __restrict__ h, const float* __restrict__ Wc3,
                                                  const float* __restrict__ bc3, float* __restrict__ out) {
  __shared__ float Ws[13][257];
  int bx = blockIdx.x;  // B*8
  int b = bx >> 3, n0 = (bx & 7) * 256;
  int t = threadIdx.x;
  for (int e = t; e < 13 * 256; e += 256) { int o = e >> 8, c = e & 255; Ws[o][c] = Wc3[o * 256 + c]; }
  __syncthreads();
  float s[13];
  #pragma unroll
  for (int o = 0; o < 13; ++o) s[o] = 0.f;
  const float* hb = h + (size_t)b * 256 * N + n0 + t;
  #pragma unroll 4
  for (int c = 0; c < 256; ++c) {
    float hv = hb[(size_t)c * N];
    #pragma unroll
    for (int o = 0; o < 13; ++o) s[o] = fmaf(Ws[o][c], hv, s[o]);
  }
  #pragma unroll
  for (int o = 0; o < 13; ++o) out[((size_t)b * 13 + o) * N + n0 + t] = s[o] + bc3[o];
}

__global__ void init_kernel(float* __restrict__ premax) {
  int i = blockIdx.x * 256 + threadIdx.x;
  if (i < 8192) premax[i] = -3.402823466e38f;
}

}  // namespace

extern "C" void kernel_launch(void* const* d_in, const int* in_sizes, int n_in,
                              void* d_out, int out_size, void* d_ws, size_t ws_size,
                              hipStream_t stream) {
  const float* x   = (const float*)d_in[0];
  const float* We1 = (const float*)d_in[1];
  const float* be1 = (const float*)d_in[2];
  const float* We2 = (const float*)d_in[3];
  const float* be2 = (const float*)d_in[4];
  const float* Wq  = (const float*)d_in[5];
  const float* Wk  = (const float*)d_in[6];
  const float* Wt  = (const float*)d_in[7];
  const float* bt  = (const float*)d_in[8];
  const float* Wf  = (const float*)d_in[9];
  const float* bf  = (const float*)d_in[10];
  const float* Wc1 = (const float*)d_in[11];
  const float* bc1 = (const float*)d_in[12];
  const float* Wc2 = (const float*)d_in[13];
  const float* bc2 = (const float*)d_in[14];
  const float* Wc3 = (const float*)d_in[15];
  const float* bc3 = (const float*)d_in[16];
  float* out = (float*)d_out;

  char* w = (char*)d_ws;
  size_t off = 0;
  auto take = [&](size_t nbytes) { void* p = w + off; off += (nbytes + 255) & ~(size_t)255; return p; };
  int*    idx1   = (int*)   take((size_t)B * N * KNN * 4);
  int*    idx2   = (int*)   take((size_t)B * N * KNN * 4);
  float*  f1     = (float*) take((size_t)B * 64 * N * 4);
  float*  f2     = (float*) take((size_t)B * 64 * N * 4);
  float*  f1t    = (float*) take((size_t)B * N * 64 * 4);
  double* xx2d   = (double*)take((size_t)B * N * 8);
  double* epart  = (double*)take((size_t)B * N * 128 * 8);
  float*  emax   = (float*) take((size_t)B * 64 * N * 4);
  float*  ems    = (float*) take(128 * 4);
  float*  feat   = (float*) take((size_t)B * 128 * N * 4);
  float*  cat    = (float*) take((size_t)B * 512 * N * 4);
  float*  xq     = (float*) take((size_t)B * N * 32 * 4);
  float*  xk     = (float*) take((size_t)B * 32 * N * 4);
  float*  rowmax = (float*) take((size_t)B * N * 4);
  float*  rowsum = (float*) take((size_t)B * N * 4);
  float*  rowpart= (float*) take((size_t)4 * B * N * 2 * 4);
  float*  ubuf   = (float*) take((size_t)B * 256 * N * 4);  // SA: tpre (2nd half) ; later: pre2
  float*  tpre   = ubuf + (size_t)B * 128 * N;
  float*  pre2   = ubuf;
  float*  bnstats= (float*) take(2048 * 4);
  float*  fps    = (float*) take((size_t)1024 * 256 * 4);
  float*  fps2   = (float*) take((size_t)1024 * 256 * 4);
  float*  premax = (float*) take((size_t)B * 1024 * 4);
  float*  gbuf   = (float*) take((size_t)B * 1024 * 4);
  float*  gproj  = (float*) take((size_t)B * 512 * 4);
  float*  pre1   = (float*) take((size_t)B * 512 * N * 4);
  // aliases (phase-disjoint): Yp (SA partial Y, 4*B*128*N) <-> pre1 ; cspart (4*B*N) <-> fps
  float*  Yp     = pre1;
  float*  cspart = fps;
  (void)ws_size; (void)in_sizes; (void)n_in; (void)out_size;

  init_kernel<<<32, 256, 0, stream>>>(premax);

  // EdgeConv block 1
  knn1_kernel<<<B * N, 256, 0, stream>>>(x, idx1);
  edge1_kernel<<<B * N, 256, 0, stream>>>(x, idx1, We1, be1, emax, epart);
  edge_stats_kernel<<<64, 256, 0, stream>>>(epart, ems);
  edge_finish_kernel<<<B * 64 * N / 256, 256, 0, stream>>>(emax, ems, f1, f1t);

  // EdgeConv block 2
  xx2_kernel<<<B * N / 256, 256, 0, stream>>>(f1, xx2d);
  knn2_kernel<<<B * N / 4, 256, 0, stream>>>(f1, f1t, xx2d, idx2);
  edge2_kernel<<<B * 512, 256, 0, stream>>>(f1t, idx2, We2, be2, emax, epart);
  edge_stats_kernel<<<64, 256, 0, stream>>>(epart, ems);
  edge_finish_kernel<<<B * 64 * N / 256, 256, 0, stream>>>(emax, ems, f2, nullptr);
  concat_feat_kernel<<<B * 128 * N / 256, 256, 0, stream>>>(f1, f2, feat);

  // 4 SA layers
  for (int lay = 0; lay < 4; ++lay) {
    const float* xs = lay ? cat : feat;
    int bstride = lay ? 512 * N : 128 * N;
    int coff = lay ? (lay - 1) * 128 : 0;
    sa_qk_kernel<<<B * 32, 256, 0, stream>>>(xs, bstride, coff, Wq + lay * 32 * 128, Wk + lay * 32 * 128, xq, xk);
    sa_rowstats_kernel<<<512, 256, 0, stream>>>(xq, xk, rowpart);
    rowstats_merge_kernel<<<B * N / 256, 256, 0, stream>>>(rowpart, rowmax, rowsum);
    sa_attny_kernel<<<B * 32 * 4, 256, 0, stream>>>(xs, bstride, coff, xq, xk, rowmax, rowsum, Yp, cspart);
    sa_wt_kernel<<<B * 32, 256, 0, stream>>>(xs, bstride, coff, Yp, cspart, Wt + lay * 128 * 128, bt + lay * 128, tpre);
    chanstats_kernel<<<128, 256, 0, stream>>>(tpre, bnstats, 128);
    sa_out_kernel<<<B * 128 * N / 256, 256, 0, stream>>>(tpre, bnstats, xs, bstride, coff, cat, lay);
  }

  // fuse -> g
  fuse_kernel<<<B * 8 * 16, 256, 0, stream>>>(cat, Wf, bf, fps, fps2, premax);
  fuse_stats_kernel<<<1024, 128, 0, stream>>>(fps, fps2, bnstats);
  g_kernel<<<B * 1024 / 256, 256, 0, stream>>>(premax, bnstats, gbuf);

  // Wc1 (split: g-projection + cat GEMM)
  gproj_kernel<<<B * 512 / 256, 256, 0, stream>>>(Wc1, gbuf, gproj);
  mlp_gemm_kernel<<<B * 4 * 16, 256, 0, stream>>>(cat, 512, Wc1, 1536, 1024, bc1, gproj, 512, pre1);
  chanstats_kernel<<<512, 256, 0, stream>>>(pre1, bnstats, 512);
  bnrelu_inplace_kernel<<<B * 512 * N / 256, 256, 0, stream>>>(pre1, bnstats, 512);

  // Wc2
  mlp_gemm_kernel<<<B * 2 * 16, 256, 0, stream>>>(pre1, 512, Wc2, 512, 0, bc2, nullptr, 256, pre2);
  chanstats_kernel<<<256, 256, 0, stream>>>(pre2, bnstats, 256);
  bnrelu_inplace_kernel<<<B * 256 * N / 256, 256, 0, stream>>>(pre2, bnstats, 256);

  // Wc3
  wc3_kernel<<<B * 8, 256, 0, stream>>>(pre2, Wc3, bc3, out);
}

// Round 12
// 2299.745 us; speedup vs baseline: 1.0224x; 1.0224x over previous
//
#include <hip/hip_runtime.h>
#include <math.h>

#define DEV static __device__ __forceinline__

namespace {

constexpr int B = 8;
constexpr int N = 2048;     // points
constexpr int KNN = 32;     // neighbors
constexpr float BNEPS = 1e-5f;

DEV unsigned f2key(float f) {
  unsigned u = __float_as_uint(f);
  return (u & 0x80000000u) ? ~u : (u | 0x80000000u);  // monotone float->uint
}

DEV void atomicMaxFloat(float* addr, float val) {
  if (val >= 0.0f) atomicMax((int*)addr, __float_as_int(val));
  else atomicMin((unsigned int*)addr, (unsigned int)__float_as_int(val));
}

// ---------- radix top-32 select over 256 threads x NK register keys ----------
struct SelScratch {
  unsigned hist[256];
  int ss[257];
  int bin;
  int cnt;
};

template <int NK>
DEV unsigned long long radix_select32(const unsigned long long (&keys)[NK], SelScratch& s) {
  const int t = threadIdx.x;
  const int lane = t & 63, wave = t >> 6;
  unsigned long long prefix = 0; unsigned long long T = 0;
  int needed = KNN;
  bool done = false;
  for (int level = 0; level < 8 && !done; ++level) {
    int shift = 56 - 8 * level;
    s.hist[t] = 0;
    __syncthreads();
    unsigned long long maskhi = level ? (~0ull << (64 - 8 * level)) : 0ull;
    #pragma unroll
    for (int j = 0; j < NK; ++j) {
      if ((keys[j] & maskhi) == prefix)
        atomicAdd(&s.hist[(unsigned)(keys[j] >> shift) & 255u], 1u);
    }
    __syncthreads();
    if (wave == 0) {
      unsigned h0 = s.hist[4 * lane], h1 = s.hist[4 * lane + 1], h2 = s.hist[4 * lane + 2], h3 = s.hist[4 * lane + 3];
      unsigned s3 = h3, s2 = h2 + s3, s1 = h1 + s2, s0 = h0 + s1;
      unsigned suf = s0;
      #pragma unroll
      for (int off = 1; off < 64; off <<= 1) {
        unsigned v = __shfl_down(suf, off);
        if (lane + off < 64) suf += v;
      }
      unsigned above = suf - s0;
      s.ss[4 * lane] = (int)(s0 + above); s.ss[4 * lane + 1] = (int)(s1 + above);
      s.ss[4 * lane + 2] = (int)(s2 + above); s.ss[4 * lane + 3] = (int)(s3 + above);
      if (lane == 63) s.ss[256] = 0;
    }
    __syncthreads();
    if (s.ss[t] >= needed && s.ss[t + 1] < needed) s.bin = t;
    __syncthreads();
    int bin = s.bin;
    int hc = (int)s.hist[bin];
    needed -= s.ss[bin + 1];
    prefix |= ((unsigned long long)(unsigned)bin) << shift;
    if (needed == hc) { T = prefix; done = true; }
    __syncthreads();
  }
  return T;
}

template <int NK>
DEV void collect32(const unsigned long long (&keys)[NK], unsigned long long T, SelScratch& s,
                   int* __restrict__ out) {
  if (threadIdx.x == 0) s.cnt = 0;
  __syncthreads();
  #pragma unroll
  for (int j = 0; j < NK; ++j) {
    if (keys[j] >= T) {
      int pos = atomicAdd(&s.cnt, 1);
      out[pos] = (int)~(unsigned)keys[j];
    }
  }
  __syncthreads();
}

// ---------------- KNN 1 (C=3), exact f64 distances, radix select ----------------
__global__ __launch_bounds__(256) void knn1_kernel(const float* __restrict__ x, int* __restrict__ idx) {
  __shared__ SelScratch s;
  __shared__ double cc[3];
  int bn = blockIdx.x, b = bn >> 11, n = bn & (N - 1);
  int t = threadIdx.x;
  const float* xb = x + (size_t)b * 3 * N;
  if (t < 3) cc[t] = (double)xb[(size_t)t * N + n];
  __syncthreads();
  double cx = cc[0], cy = cc[1], cz = cc[2];
  unsigned long long keys[8];
  #pragma unroll
  for (int j = 0; j < 8; ++j) {
    int m = t + 256 * j;
    double dx = (double)xb[m] - cx, dy = (double)xb[N + m] - cy, dz = (double)xb[2 * N + m] - cz;
    double pd = -(dx * dx + dy * dy + dz * dz);
    keys[j] = ((unsigned long long)f2key((float)pd) << 32) | (unsigned)~m;
  }
  __syncthreads();
  unsigned long long T = radix_select32(keys, s);
  collect32(keys, T, s, idx + (size_t)bn * KNN);
}

// ---------------- EdgeConv 1 (6 -> 64): non-fma sequential-c, dot-then-bias ----------------
__global__ __launch_bounds__(256) void edge1_kernel(const float* __restrict__ x, const int* __restrict__ idx,
    const float* __restrict__ We1, const float* __restrict__ be1,
    float* __restrict__ emax, double* __restrict__ epart) {
  __shared__ float Ws[6][65];   // [c][o]
  __shared__ float fs[6][33];   // [c][k]
  __shared__ float es[64][33];  // [o][k]
  __shared__ int  is[KNN];
  int bn = blockIdx.x, b = bn >> 11, n = bn & (N - 1);
  int t = threadIdx.x;
  if (t < KNN) is[t] = idx[(size_t)bn * KNN + t];
  for (int e = t; e < 64 * 6; e += 256) Ws[e % 6][e / 6] = We1[e];  // We1[o][c]
  __syncthreads();
  const float* xb = x + (size_t)b * 3 * N;
  for (int e = t; e < 6 * KNN; e += 256) {
    int c = e >> 5, k = e & 31;
    int m = is[k];
    fs[c][k] = (c < 3) ? (xb[(size_t)c * N + m] - xb[(size_t)c * N + n]) : xb[(size_t)(c - 3) * N + n];
  }
  __syncthreads();
  int k = t & 31, orow = t >> 5;
  float acc[8];
  #pragma unroll
  for (int j = 0; j < 8; ++j) acc[j] = 0.0f;
  #pragma unroll
  for (int c = 0; c < 6; ++c) {
    float fv = fs[c][k];
    #pragma unroll
    for (int j = 0; j < 8; ++j) acc[j] = __fadd_rn(acc[j], __fmul_rn(Ws[c][orow * 8 + j], fv));
  }
  #pragma unroll
  for (int j = 0; j < 8; ++j) es[orow * 8 + j][k] = __fadd_rn(acc[j], be1[orow * 8 + j]);
  __syncthreads();
  if (t < 64) {
    double sum = 0, s2 = 0; float mx = -3.402823466e38f;
    #pragma unroll 8
    for (int kk = 0; kk < KNN; ++kk) {
      float v = es[t][kk]; double dv = (double)v;
      sum += dv; s2 = fma(dv, dv, s2); mx = fmaxf(mx, v);
    }
    emax[((size_t)b * 64 + t) * N + n] = mx;
    epart[(size_t)bn * 128 + t] = sum;
    epart[(size_t)bn * 128 + 64 + t] = s2;
  }
}

// reduce per-block edge partials (f64) -> per-channel mean / var (f32 outputs)
__global__ __launch_bounds__(256) void edge_stats_kernel(const double* __restrict__ epart, float* __restrict__ ems) {
  __shared__ double r1[256], r2[256];
  int o = blockIdx.x, t = threadIdx.x;
  double s = 0, s2 = 0;
  for (int i = t; i < B * N; i += 256) { s += epart[(size_t)i * 128 + o]; s2 += epart[(size_t)i * 128 + 64 + o]; }
  r1[t] = s; r2[t] = s2; __syncthreads();
  for (int st = 128; st > 0; st >>= 1) { if (t < st) { r1[t] += r1[t + st]; r2[t] += r2[t + st]; } __syncthreads(); }
  if (t == 0) {
    double cnt = (double)(B * N * KNN);
    double m = r1[0] / cnt, v = r2[0] / cnt - m * m;
    ems[o] = (float)m; ems[64 + o] = (float)v;
  }
}

// BN+ReLU finish; optionally also writes the [b][n][c] transposed copy
__global__ __launch_bounds__(256) void edge_finish_kernel(const float* __restrict__ emax, const float* __restrict__ ems,
                                                          float* __restrict__ f, float* __restrict__ ft) {
  size_t i = (size_t)blockIdx.x * 256 + threadIdx.x;  // B*64*N
  int c = (int)((i >> 11) & 63);
  float sd = sqrtf(ems[64 + c] + BNEPS);
  float v = (emax[i] - ems[c]) / sd;
  v = v > 0.f ? v : 0.f;
  f[i] = v;
  if (ft) {
    int n = (int)(i & (N - 1)); int b = (int)(i >> 17);
    ft[((size_t)b * N + n) * 64 + c] = v;
  }
}

__global__ __launch_bounds__(256) void xx2_kernel(const float* __restrict__ f1, double* __restrict__ xx2) {
  int i = blockIdx.x * 256 + threadIdx.x;  // B*N
  int b = i >> 11, n = i & (N - 1);
  const float* p = f1 + (size_t)b * 64 * N + n;
  double s = 0;
  #pragma unroll 16
  for (int c = 0; c < 64; ++c) { double v = (double)p[(size_t)c * N]; s = fma(v, v, s); }
  xx2[i] = s;
}

// ---------------- KNN 2 (C=64), f64 distances, 4 rows/block, radix select ----------------
__global__ __launch_bounds__(256) void knn2_kernel(const float* __restrict__ f1, const float* __restrict__ f1t,
                                                   const double* __restrict__ xx2, int* __restrict__ idx) {
  __shared__ SelScratch s;
  __shared__ double ctr[4][64];
  __shared__ unsigned long long stash[2][8][256];
  int bx = blockIdx.x, b = bx >> 9, n0 = (bx & 511) * 4;
  int t = threadIdx.x;
  { int i = t >> 6, c = t & 63; ctr[i][c] = (double)f1t[((size_t)b * N + n0 + i) * 64 + c]; }
  __syncthreads();
  const float* fb = f1 + (size_t)b * 64 * N;
  const double* xxb = xx2 + (size_t)b * N;
  double xxn0 = xxb[n0], xxn1 = xxb[n0 + 1], xxn2 = xxb[n0 + 2], xxn3 = xxb[n0 + 3];
  int mbase = t * 8;
  double xm[8];
  #pragma unroll
  for (int j = 0; j < 8; ++j) xm[j] = xxb[mbase + j];
  double a[4][8];
  #pragma unroll
  for (int i = 0; i < 4; ++i)
    #pragma unroll
    for (int j = 0; j < 8; ++j) a[i][j] = 0.0;
  #pragma unroll 4
  for (int c = 0; c < 64; ++c) {
    double w0 = ctr[0][c], w1 = ctr[1][c], w2 = ctr[2][c], w3 = ctr[3][c];
    float4 fA = *(const float4*)&fb[(size_t)c * N + mbase];
    float4 fB = *(const float4*)&fb[(size_t)c * N + mbase + 4];
    float fv[8] = {fA.x, fA.y, fA.z, fA.w, fB.x, fB.y, fB.z, fB.w};
    #pragma unroll
    for (int j = 0; j < 8; ++j) {
      double v = (double)fv[j];
      a[0][j] = fma(v, w0, a[0][j]);
      a[1][j] = fma(v, w1, a[1][j]);
      a[2][j] = fma(v, w2, a[2][j]);
      a[3][j] = fma(v, w3, a[3][j]);
    }
  }
  unsigned long long k0[8], k1[8];
  #pragma unroll
  for (int j = 0; j < 8; ++j) {
    unsigned long long lo = (unsigned)~(mbase + j);
    k0[j] = ((unsigned long long)f2key((float)(-xxn0 + 2.0 * a[0][j] - xm[j])) << 32) | lo;
    k1[j] = ((unsigned long long)f2key((float)(-xxn1 + 2.0 * a[1][j] - xm[j])) << 32) | lo;
    stash[0][j][t] = ((unsigned long long)f2key((float)(-xxn2 + 2.0 * a[2][j] - xm[j])) << 32) | lo;
    stash[1][j][t] = ((unsigned long long)f2key((float)(-xxn3 + 2.0 * a[3][j] - xm[j])) << 32) | lo;
  }
  __syncthreads();
  unsigned long long T;
  T = radix_select32(k0, s); collect32(k0, T, s, idx + ((size_t)b * N + n0 + 0) * KNN);
  T = radix_select32(k1, s); collect32(k1, T, s, idx + ((size_t)b * N + n0 + 1) * KNN);
  unsigned long long kk[8];
  #pragma unroll
  for (int j = 0; j < 8; ++j) kk[j] = stash[0][j][t];
  T = radix_select32(kk, s); collect32(kk, T, s, idx + ((size_t)b * N + n0 + 2) * KNN);
  #pragma unroll
  for (int j = 0; j < 8; ++j) kk[j] = stash[1][j][t];
  T = radix_select32(kk, s); collect32(kk, T, s, idx + ((size_t)b * N + n0 + 3) * KNN);
}

// ---------------- EdgeConv 2 (128 -> 64), 4 points/block, register tile 4o x 8k ----------------
__global__ __launch_bounds__(256) void edge2_kernel(const float* __restrict__ f1t, const int* __restrict__ idx,
    const float* __restrict__ We2, const float* __restrict__ be2,
    float* __restrict__ emax, double* __restrict__ epart) {
  __shared__ __align__(16) float smem[8448];
  __shared__ int is[4][32];
  float* Wsb = smem;                // [c][o] stride 68
  float* fsb = smem + 2176;         // [p][c][k] stride 36 in k
  int bx = blockIdx.x;  // B * 512
  int b = bx >> 9, n0 = (bx & 511) * 4;
  int t = threadIdx.x;
  if (t < 128) is[t >> 5][t & 31] = idx[((size_t)b * N + n0 + (t >> 5)) * KNN + (t & 31)];
  int o4 = t & 15, kq = (t >> 4) & 3, p = t >> 6;
  float acc[4][8];
  #pragma unroll
  for (int i = 0; i < 4; ++i)
    #pragma unroll
    for (int j = 0; j < 8; ++j) acc[i][j] = 0.f;
  const float* fbt = f1t + (size_t)b * N * 64;
  for (int cc = 0; cc < 4; ++cc) {
    int c0 = cc * 32;
    __syncthreads();
    for (int e = t; e < 2048; e += 256) { int o = e >> 5, c = e & 31; Wsb[c * 68 + o] = We2[(size_t)o * 128 + c0 + c]; }
    for (int e = t; e < 4096; e += 256) {
      int c = e & 31, kk = (e >> 5) & 31, pp = e >> 10;
      int m = is[pp][kk];
      int cg = c0 + c;
      float v = (cg < 64) ? (fbt[(size_t)m * 64 + cg] - fbt[(size_t)(n0 + pp) * 64 + cg])
                          : fbt[(size_t)(n0 + pp) * 64 + (cg - 64)];
      fsb[(pp * 32 + c) * 36 + kk] = v;
    }
    __syncthreads();
    #pragma unroll 4
    for (int c = 0; c < 32; ++c) {
      float4 w4 = *(const float4*)&Wsb[c * 68 + o4 * 4];
      float4 fa = *(const float4*)&fsb[(p * 32 + c) * 36 + kq * 8];
      float4 fb = *(const float4*)&fsb[(p * 32 + c) * 36 + kq * 8 + 4];
      float wv[4]; *(float4*)wv = w4;
      float fv[8]; *(float4*)fv = fa; *(float4*)(fv + 4) = fb;
      #pragma unroll
      for (int i = 0; i < 4; ++i)
        #pragma unroll
        for (int j = 0; j < 8; ++j) acc[i][j] = fmaf(wv[i], fv[j], acc[i][j]);
    }
  }
  __syncthreads();  // before overwriting phase-A LDS with es
  {
    float bv[4]; *(float4*)bv = *(const float4*)&be2[o4 * 4];
    #pragma unroll
    for (int j = 0; j < 8; ++j) {
      int k = kq * 8 + j;
      float4 v4 = make_float4(acc[0][j] + bv[0], acc[1][j] + bv[1], acc[2][j] + bv[2], acc[3][j] + bv[3]);
      *(float4*)&smem[k * 264 + p * 64 + o4 * 4] = v4;
    }
  }
  __syncthreads();
  {
    int pp = t >> 6, o = t & 63;
    double sum = 0, s2 = 0; float mx = -3.402823466e38f;
    #pragma unroll 8
    for (int kk = 0; kk < KNN; ++kk) {
      float v = smem[kk * 264 + pp * 64 + o]; double dv = (double)v;
      sum += dv; s2 = fma(dv, dv, s2); mx = fmaxf(mx, v);
    }
    int n = n0 + pp;
    emax[((size_t)b * 64 + o) * N + n] = mx;
    epart[((size_t)b * N + n) * 128 + o] = sum;
    epart[((size_t)b * N + n) * 128 + 64 + o] = s2;
  }
}

__global__ __launch_bounds__(256) void concat_feat_kernel(const float* __restrict__ f1, const float* __restrict__ f2,
                                                          float* __restrict__ feat) {
  size_t i = (size_t)blockIdx.x * 256 + threadIdx.x;  // B*128*N
  int n = (int)(i & (N - 1)); int c = (int)((i >> 11) & 127); int b = (int)(i >> 18);
  feat[i] = (c < 64) ? f1[((size_t)b * 64 + c) * N + n] : f2[((size_t)b * 64 + (c - 64)) * N + n];
}

// generic: per-channel mean/var from per-part (sum, sumsq) partials
__global__ __launch_bounds__(256) void stats_from_parts_kernel(const float* __restrict__ p1,
    const float* __restrict__ p2, float* __restrict__ ms, int C, int P) {
  __shared__ double r1[256], r2[256];
  int o = blockIdx.x, t = threadIdx.x;
  double s = 0, s2 = 0;
  for (int i = t; i < P; i += 256) { s += (double)p1[(size_t)o * P + i]; s2 += (double)p2[(size_t)o * P + i]; }
  r1[t] = s; r2[t] = s2; __syncthreads();
  for (int st = 128; st > 0; st >>= 1) { if (t < st) { r1[t] += r1[t + st]; r2[t] += r2[t + st]; } __syncthreads(); }
  if (t == 0) {
    double cnt = (double)(B * N);
    double m = r1[0] / cnt, v = r2[0] / cnt - m * m;
    ms[o] = (float)m; ms[C + o] = (float)v;
  }
}

// ---------------- SA layer ----------------
__global__ __launch_bounds__(256) void sa_qk_kernel(const float* __restrict__ xs, int xs_bstride, int xs_coff,
    const float* __restrict__ Wq, const float* __restrict__ Wk,
    float* __restrict__ xq, float* __restrict__ xk) {
  __shared__ __align__(16) float Ws[32][68];  // [c][o]
  __shared__ __align__(16) float vs[32][68];  // [c][n]
  int bx = blockIdx.x, b = bx >> 5, n0 = (bx & 31) * 64;
  int t = threadIdx.x;
  int tc = t >> 4, tm = t & 15;
  float acc[4][4];
  #pragma unroll
  for (int i = 0; i < 4; ++i)
    #pragma unroll
    for (int j = 0; j < 4; ++j) acc[i][j] = 0.f;
  for (int cc = 0; cc < 4; ++cc) {
    int c0 = cc * 32;
    __syncthreads();
    for (int e = t; e < 512; e += 256) {
      int o = (e & 15) | ((e >> 7) << 4), cq = (e >> 4) & 7;
      float4 w4 = (o < 32) ? *(const float4*)&Wq[o * 128 + c0 + cq * 4]
                           : *(const float4*)&Wk[(o - 32) * 128 + c0 + cq * 4];
      Ws[cq * 4 + 0][o] = w4.x; Ws[cq * 4 + 1][o] = w4.y; Ws[cq * 4 + 2][o] = w4.z; Ws[cq * 4 + 3][o] = w4.w;
    }
    for (int e = t; e < 512; e += 256) {
      int c = e >> 4, nq = e & 15;
      *(float4*)&vs[c][nq * 4] =
          *(const float4*)&xs[(size_t)b * xs_bstride + (size_t)(xs_coff + c0 + c) * N + n0 + nq * 4];
    }
    __syncthreads();
    #pragma unroll 4
    for (int c = 0; c < 32; ++c) {
      float4 w4 = *(const float4*)&Ws[c][tc * 4];
      float4 v4 = *(const float4*)&vs[c][tm * 4];
      float wv[4] = {w4.x, w4.y, w4.z, w4.w};
      float vv[4] = {v4.x, v4.y, v4.z, v4.w};
      #pragma unroll
      for (int i = 0; i < 4; ++i)
        #pragma unroll
        for (int j = 0; j < 4; ++j) acc[i][j] = fmaf(wv[i], vv[j], acc[i][j]);
    }
  }
  #pragma unroll
  for (int i = 0; i < 4; ++i) {
    int o2 = tc * 4 + i;
    if (o2 < 32) {
      #pragma unroll
      for (int j = 0; j < 4; ++j) {
        int n = n0 + tm * 4 + j;
        xq[((size_t)b * N + n) * 32 + o2] = acc[i][j];
      }
    } else {
      float4 o4 = make_float4(acc[i][0], acc[i][1], acc[i][2], acc[i][3]);
      *(float4*)&xk[((size_t)b * 32 + (o2 - 32)) * N + n0 + tm * 4] = o4;
    }
  }
}

// GEMM-style row softmax stats (unchanged from round 9/10)
__global__ __launch_bounds__(256) void sa_rowstats_kernel(const float* __restrict__ xq, const float* __restrict__ xk,
    float* __restrict__ rowpart) {
  __shared__ __align__(16) float Qs[32][132];  // [q][row]
  __shared__ __align__(16) float Ks[32][68];   // [q][m]
  int bx = blockIdx.x;
  int rt = bx & 15, mc = (bx >> 4) & 3, b = bx >> 6;
  int n0 = rt * 128, m0 = mc * 512;
  int t = threadIdx.x, tc = t >> 4, tm = t & 15;
  for (int e = t; e < 1024; e += 256) {
    int r = (e & 15) | ((e >> 7) << 4), q4 = (e >> 4) & 7;
    float4 v = *(const float4*)&xq[((size_t)b * N + n0 + r) * 32 + q4 * 4];
    Qs[q4 * 4 + 0][r] = v.x; Qs[q4 * 4 + 1][r] = v.y; Qs[q4 * 4 + 2][r] = v.z; Qs[q4 * 4 + 3][r] = v.w;
  }
  float rm8[8], rs8[8];
  #pragma unroll
  for (int i = 0; i < 8; ++i) { rm8[i] = -3.402823466e38f; rs8[i] = 0.f; }
  for (int mt = 0; mt < 8; ++mt) {
    int mbase = m0 + mt * 64;
    __syncthreads();
    for (int e = t; e < 512; e += 256) {
      int q = e >> 4, m4 = e & 15;
      *(float4*)&Ks[q][m4 * 4] = *(const float4*)&xk[((size_t)b * 32 + q) * N + mbase + m4 * 4];
    }
    __syncthreads();
    float acc[8][4];
    #pragma unroll
    for (int jc = 0; jc < 8; ++jc)
      #pragma unroll
      for (int jm = 0; jm < 4; ++jm) acc[jc][jm] = 0.f;
    #pragma unroll 4
    for (int c = 0; c < 32; ++c) {
      float4 w0 = *(const float4*)&Qs[c][tc * 4];
      float4 w1 = *(const float4*)&Qs[c][tc * 4 + 64];
      float4 k4 = *(const float4*)&Ks[c][tm * 4];
      float wv[8] = {w0.x, w0.y, w0.z, w0.w, w1.x, w1.y, w1.z, w1.w};
      float kv[4] = {k4.x, k4.y, k4.z, k4.w};
      #pragma unroll
      for (int jc = 0; jc < 8; ++jc)
        #pragma unroll
        for (int jm = 0; jm < 4; ++jm) acc[jc][jm] = fmaf(wv[jc], kv[jm], acc[jc][jm]);
    }
    #pragma unroll
    for (int jc = 0; jc < 8; ++jc) {
      #pragma unroll
      for (int jm = 0; jm < 4; ++jm) {
        float e2 = acc[jc][jm];
        if (e2 > rm8[jc]) { rs8[jc] = rs8[jc] * __expf(rm8[jc] - e2) + 1.0f; rm8[jc] = e2; }
        else rs8[jc] += __expf(e2 - rm8[jc]);
      }
    }
  }
  #pragma unroll
  for (int jc = 0; jc < 8; ++jc) {
    float M = rm8[jc], S = rs8[jc];
    #pragma unroll
    for (int off = 1; off < 16; off <<= 1) {
      float M2 = __shfl_xor(M, off), S2 = __shfl_xor(S, off);
      float mm = fmaxf(M, M2);
      S = S * __expf(M - mm) + S2 * __expf(M2 - mm);
      M = mm;
    }
    if (tm == 0) {
      int r = n0 + tc * 4 + (jc & 3) + (jc >> 2) * 64;
      size_t o = ((size_t)mc * (B * N) + (size_t)b * N + r) * 2;
      rowpart[o] = M; rowpart[o + 1] = S;
    }
  }
}

__global__ void rowstats_merge_kernel(const float* __restrict__ rowpart,
                                      float* __restrict__ rowmax, float* __restrict__ rowsum) {
  int i = blockIdx.x * 256 + threadIdx.x;  // B*N
  float M = rowpart[(size_t)i * 2], S = rowpart[(size_t)i * 2 + 1];
  #pragma unroll
  for (int mc = 1; mc < 4; ++mc) {
    size_t o = ((size_t)mc * (B * N) + i) * 2;
    float M2 = rowpart[o], S2 = rowpart[o + 1];
    float mm = fmaxf(M, M2);
    S = S * __expf(M - mm) + S2 * __expf(M2 - mm);
    M = mm;
  }
  rowmax[i] = M; rowsum[i] = S;
}

// Y = xs @ P over an n-chunk; partial Y + colsum per chunk (unchanged)
__global__ __launch_bounds__(256) void sa_attny_kernel(const float* __restrict__ xs, int xs_bstride, int xs_coff,
    const float* __restrict__ xq, const float* __restrict__ xk,
    const float* __restrict__ rowmax, const float* __restrict__ rowsum,
    float* __restrict__ Yp, float* __restrict__ cspart) {
  __shared__ __align__(16) float qs[64][36];   // [n][q]
  __shared__ float rmv[64], rsv[64];
  __shared__ __align__(16) float Ps[64][68];   // [n][m]
  __shared__ __align__(16) float vs[64][132];  // [n][SW(c)]
  __shared__ float csr[4][64];
  int bx = blockIdx.x;
  int g = bx & 3, m0 = ((bx >> 2) & 31) * 64, b = bx >> 7;
  int t = threadIdx.x;
  int tc = t >> 4, tm = t & 15;
  int tmm = t & 63, tns = t >> 6;
  float kreg[32];
  #pragma unroll
  for (int q = 0; q < 32; ++q) kreg[q] = xk[((size_t)b * 32 + q) * N + m0 + tmm];
  float acc[2][4][4];
  #pragma unroll
  for (int h = 0; h < 2; ++h)
    #pragma unroll
    for (int i = 0; i < 4; ++i)
      #pragma unroll
      for (int j = 0; j < 4; ++j) acc[h][i][j] = 0.f;
  float cs = 0.f;
  const float* xsb = xs + (size_t)b * xs_bstride + (size_t)xs_coff * N;
  for (int nt = g * 8; nt < g * 8 + 8; ++nt) {
    int n0 = nt * 64;
    __syncthreads();
    for (int e = t; e < 512; e += 256) {
      int nn = e >> 3, qq = e & 7;
      *(float4*)&qs[nn][qq * 4] = *(const float4*)&xq[((size_t)b * N + n0 + nn) * 32 + qq * 4];
    }
    if (t < 64) { rmv[t] = rowmax[(size_t)b * N + n0 + t]; rsv[t] = 1.0f / rowsum[(size_t)b * N + n0 + t]; }
    for (int e = t; e < 128 * 64; e += 256) {
      int c = e >> 6, nn = e & 63;
      int M = (nn & 3) | (((nn >> 3) & 7) << 2);
      vs[nn][c ^ M] = xsb[(size_t)c * N + n0 + nn];
    }
    __syncthreads();
    float cp = 0.f;
    #pragma unroll 1
    for (int jj = 0; jj < 16; ++jj) {
      int nn = tns * 16 + jj;
      float ea = 0, eb = 0, ec = 0, ed = 0;
      #pragma unroll
      for (int q4 = 0; q4 < 8; ++q4) {
        float4 qv = *(const float4*)&qs[nn][q4 * 4];
        ea = fmaf(qv.x, kreg[4 * q4 + 0], ea);
        eb = fmaf(qv.y, kreg[4 * q4 + 1], eb);
        ec = fmaf(qv.z, kreg[4 * q4 + 2], ec);
        ed = fmaf(qv.w, kreg[4 * q4 + 3], ed);
      }
      float e2 = (ea + eb) + (ec + ed);
      float p = __expf(e2 - rmv[nn]) * rsv[nn];
      Ps[nn][tmm] = p; cp += p;
    }
    csr[tns][tmm] = cp;
    __syncthreads();
    if (t < 64) cs += csr[0][t] + csr[1][t] + csr[2][t] + csr[3][t];
    #pragma unroll 1
    for (int nn8 = 0; nn8 < 8; ++nn8) {
      int s2x = nn8 << 2;
      int b0 = (tc * 4) ^ s2x;
      #pragma unroll
      for (int kk = 0; kk < 8; ++kk) {
        int nn = nn8 * 8 + kk;
        const int k = kk & 3;
        float4 pa = *(const float4*)&Ps[nn][tm * 4];
        float4 q0 = *(const float4*)&vs[nn][b0];
        float4 q1 = *(const float4*)&vs[nn][64 + b0];
        float pv[4]; *(float4*)pv = pa;
        float xr0[4]; *(float4*)xr0 = q0;
        float xr1[4]; *(float4*)xr1 = q1;
        float xv0[4] = {xr0[0 ^ k], xr0[1 ^ k], xr0[2 ^ k], xr0[3 ^ k]};
        float xv1[4] = {xr1[0 ^ k], xr1[1 ^ k], xr1[2 ^ k], xr1[3 ^ k]};
        #pragma unroll
        for (int i = 0; i < 4; ++i)
          #pragma unroll
          for (int jm = 0; jm < 4; ++jm) {
            acc[0][i][jm] = fmaf(xv0[i], pv[jm], acc[0][i][jm]);
            acc[1][i][jm] = fmaf(xv1[i], pv[jm], acc[1][i][jm]);
          }
      }
    }
  }
  #pragma unroll
  for (int h = 0; h < 2; ++h)
    #pragma unroll
    for (int i = 0; i < 4; ++i) {
      float4 o4 = make_float4(acc[h][i][0], acc[h][i][1], acc[h][i][2], acc[h][i][3]);
      *(float4*)&Yp[(((size_t)g * B + b) * 128 + h * 64 + tc * 4 + i) * N + m0 + tm * 4] = o4;
    }
  if (t < 64) cspart[((size_t)g * B + b) * N + m0 + t] = cs;
}

// tpre = Wt @ (xs - Y/(1e-6+colsum)) + bt ; also emits BN partials per (o, block)
__global__ __launch_bounds__(256) void sa_wt_kernel(const float* __restrict__ xs, int xs_bstride, int xs_coff,
    const float* __restrict__ Yp, const float* __restrict__ cspart,
    const float* __restrict__ Wt, const float* __restrict__ bt,
    float* __restrict__ tpre, float* __restrict__ wtps, float* __restrict__ wtps2) {
  __shared__ __align__(16) float Ws[32][132];
  __shared__ __align__(16) float vs[32][68];
  __shared__ __align__(16) float inv[64];
  int bx = blockIdx.x, b = bx >> 5, n0 = (bx & 31) * 64;
  int part = bx;  // [0,256)
  int t = threadIdx.x;
  if (t < 64) {
    float s = 0;
    #pragma unroll
    for (int g = 0; g < 4; ++g) s += cspart[((size_t)g * B + b) * N + n0 + t];
    inv[t] = 1.0f / (1e-6f + s);
  }
  int tc = t >> 4, tm = t & 15;
  float acc[8][4];
  #pragma unroll
  for (int jc = 0; jc < 8; ++jc)
    #pragma unroll
    for (int jm = 0; jm < 4; ++jm) acc[jc][jm] = 0.f;
  for (int cc = 0; cc < 4; ++cc) {
    int c0 = cc * 32;
    __syncthreads();
    for (int e = t; e < 1024; e += 256) {
      int o = (e & 15) | ((e >> 7) << 4), cq = (e >> 4) & 7;
      float4 w4 = *(const float4*)&Wt[o * 128 + c0 + cq * 4];
      Ws[cq * 4 + 0][o] = w4.x; Ws[cq * 4 + 1][o] = w4.y; Ws[cq * 4 + 2][o] = w4.z; Ws[cq * 4 + 3][o] = w4.w;
    }
    for (int e = t; e < 512; e += 256) {
      int c = e >> 4, nq = e & 15;
      float4 xv = *(const float4*)&xs[(size_t)b * xs_bstride + (size_t)(xs_coff + c0 + c) * N + n0 + nq * 4];
      float4 ys = make_float4(0.f, 0.f, 0.f, 0.f);
      #pragma unroll
      for (int g = 0; g < 4; ++g) {
        float4 yv = *(const float4*)&Yp[(((size_t)g * B + b) * 128 + c0 + c) * N + n0 + nq * 4];
        ys.x += yv.x; ys.y += yv.y; ys.z += yv.z; ys.w += yv.w;
      }
      float4 iv = *(const float4*)&inv[nq * 4];
      float4 r = make_float4(xv.x - ys.x * iv.x, xv.y - ys.y * iv.y, xv.z - ys.z * iv.z, xv.w - ys.w * iv.w);
      *(float4*)&vs[c][nq * 4] = r;
    }
    __syncthreads();
    #pragma unroll 4
    for (int c = 0; c < 32; ++c) {
      float4 w0 = *(const float4*)&Ws[c][tc * 4];
      float4 w1 = *(const float4*)&Ws[c][tc * 4 + 64];
      float4 v4 = *(const float4*)&vs[c][tm * 4];
      float wv[8] = {w0.x, w0.y, w0.z, w0.w, w1.x, w1.y, w1.z, w1.w};
      float vv[4] = {v4.x, v4.y, v4.z, v4.w};
      #pragma unroll
      for (int jc = 0; jc < 8; ++jc)
        #pragma unroll
        for (int jm = 0; jm < 4; ++jm) acc[jc][jm] = fmaf(wv[jc], vv[jm], acc[jc][jm]);
    }
  }
  #pragma unroll
  for (int jc = 0; jc < 8; ++jc) {
    int o2 = tc * 4 + (jc & 3) + (jc >> 2) * 64;
    float bias = bt[o2];
    float v0 = acc[jc][0] + bias, v1 = acc[jc][1] + bias, v2 = acc[jc][2] + bias, v3 = acc[jc][3] + bias;
    float4 o4 = make_float4(v0, v1, v2, v3);
    *(float4*)&tpre[((size_t)b * 128 + o2) * N + n0 + tm * 4] = o4;
    double s = (double)v0 + (double)v1 + (double)v2 + (double)v3;
    double s2 = fma((double)v0, (double)v0, fma((double)v1, (double)v1,
                fma((double)v2, (double)v2, (double)v3 * (double)v3)));
    #pragma unroll
    for (int off = 1; off < 16; off <<= 1) {
      s += __shfl_xor(s, off);
      s2 += __shfl_xor(s2, off);
    }
    if (tm == 0) {
      wtps[(size_t)o2 * 256 + part] = (float)s;
      wtps2[(size_t)o2 * 256 + part] = (float)s2;
    }
  }
}

__global__ __launch_bounds__(256) void sa_out_kernel(const float* __restrict__ tpre, const float* __restrict__ ms,
    const float* __restrict__ xs, int xs_bstride, int xs_coff, float* __restrict__ cat, int lay) {
  size_t i = (size_t)blockIdx.x * 256 + threadIdx.x;  // B*128*N
  int n = (int)(i & (N - 1)); int c = (int)((i >> 11) & 127); int b = (int)(i >> 18);
  float sd = sqrtf(ms[128 + c] + BNEPS);
  float v = (tpre[i] - ms[c]) / sd;
  v = v > 0.f ? v : 0.f;
  float xv = xs[(size_t)b * xs_bstride + (size_t)(xs_coff + c) * N + n];
  cat[((size_t)b * 512 + lay * 128 + c) * N + n] = xv + v;
}

// fuse: Wf@cat+bf -> 8x8 register tile; stats epilogue in registers
__global__ __launch_bounds__(256) void fuse_kernel(const float* __restrict__ cat, const float* __restrict__ Wf,
    const float* __restrict__ bf, float* __restrict__ fps, float* __restrict__ fps2, float* __restrict__ premax) {
  __shared__ __align__(16) float Ws[32][132];
  __shared__ __align__(16) float vs[32][132];
  int bx = blockIdx.x;
  int b = bx >> 7, o0 = ((bx >> 4) & 7) * 128, ntile = bx & 15, n0 = ntile * 128;
  int part = b * 16 + ntile;  // [0,128)
  int t = threadIdx.x, ty = t >> 4, tx = t & 15;
  float acc[8][8];
  #pragma unroll
  for (int jo = 0; jo < 8; ++jo)
    #pragma unroll
    for (int ji = 0; ji < 8; ++ji) acc[jo][ji] = 0.f;
  for (int cc = 0; cc < 16; ++cc) {
    int c0 = cc * 32;
    __syncthreads();
    for (int e = t; e < 1024; e += 256) {
      int o = (e & 15) | ((e >> 7) << 4), cq = (e >> 4) & 7;
      float4 w4 = *(const float4*)&Wf[(size_t)(o0 + o) * 512 + c0 + cq * 4];
      Ws[cq * 4 + 0][o] = w4.x; Ws[cq * 4 + 1][o] = w4.y; Ws[cq * 4 + 2][o] = w4.z; Ws[cq * 4 + 3][o] = w4.w;
    }
    for (int e = t; e < 1024; e += 256) {
      int c = e >> 5, nq = e & 31;
      *(float4*)&vs[c][nq * 4] = *(const float4*)&cat[((size_t)b * 512 + c0 + c) * N + n0 + nq * 4];
    }
    __syncthreads();
    #pragma unroll 4
    for (int c = 0; c < 32; ++c) {
      float4 w0 = *(const float4*)&Ws[c][ty * 4];
      float4 w1 = *(const float4*)&Ws[c][64 + ty * 4];
      float4 v0 = *(const float4*)&vs[c][tx * 4];
      float4 v1 = *(const float4*)&vs[c][64 + tx * 4];
      float wv[8] = {w0.x, w0.y, w0.z, w0.w, w1.x, w1.y, w1.z, w1.w};
      float vv[8] = {v0.x, v0.y, v0.z, v0.w, v1.x, v1.y, v1.z, v1.w};
      #pragma unroll
      for (int jo = 0; jo < 8; ++jo)
        #pragma unroll
        for (int ji = 0; ji < 8; ++ji) acc[jo][ji] = fmaf(wv[jo], vv[ji], acc[jo][ji]);
    }
  }
  #pragma unroll
  for (int jo = 0; jo < 8; ++jo) {
    int o = ty * 4 + (jo & 3) + (jo >> 2) * 64;
    float bias = bf[o0 + o];
    double s = 0, s2 = 0; float mx = -3.402823466e38f;
    #pragma unroll
    for (int ji = 0; ji < 8; ++ji) {
      float v = acc[jo][ji] + bias;
      double dv = (double)v;
      s += dv; s2 = fma(dv, dv, s2); mx = fmaxf(mx, v);
    }
    #pragma unroll
    for (int off = 1; off < 16; off <<= 1) {
      s += __shfl_xor(s, off);
      s2 += __shfl_xor(s2, off);
      mx = fmaxf(mx, __shfl_xor(mx, off));
    }
    if (tx == 0) {
      fps[(size_t)(o0 + o) * 128 + part] = (float)s;
      fps2[(size_t)(o0 + o) * 128 + part] = (float)s2;
      atomicMaxFloat(&premax[(size_t)b * 1024 + o0 + o], mx);
    }
  }
}

__global__ void g_kernel(const float* __restrict__ premax, const float* __restrict__ ms, float* __restrict__ g) {
  int i = blockIdx.x * 256 + threadIdx.x;  // B*1024
  int o = i & 1023;
  float sd = sqrtf(ms[1024 + o] + BNEPS);
  float v = (premax[i] - ms[o]) / sd;
  g[i] = v > 0.f ? v : 0.f;
}

__global__ __launch_bounds__(256) void gproj_kernel(const float* __restrict__ Wc1, const float* __restrict__ g,
                                                    float* __restrict__ gproj) {
  int i = blockIdx.x * 256 + threadIdx.x;  // B*512
  int b = i >> 9, o = i & 511;
  const float* gb = g + (size_t)b * 1024;
  const float* wr = Wc1 + (size_t)o * 1536;
  float s = 0;
  #pragma unroll 8
  for (int c = 0; c < 1024; ++c) s = fmaf(wr[c], gb[c], s);
  gproj[i] = s;
}

// 8x8 register-tile GEMM; optional input-BN+ReLU during staging; optional BN partials out
__global__ __launch_bounds__(256) void mlp_gemm_kernel(const float* __restrict__ in, int Cin,
    const float* __restrict__ W, int wstride, int wcoff,
    const float* __restrict__ bias, const float* __restrict__ extra, int Cout,
    float* __restrict__ out, const float* __restrict__ inms,
    float* __restrict__ ps, float* __restrict__ ps2) {
  __shared__ __align__(16) float Ws[32][132];
  __shared__ __align__(16) float vs[32][132];
  int otiles = Cout >> 7;
  int bx = blockIdx.x;
  int b = bx / (otiles * 16); int rem = bx % (otiles * 16);
  int o0 = (rem >> 4) * 128, n0 = (rem & 15) * 128;
  int part = b * 16 + (rem & 15);  // [0,128)
  int t = threadIdx.x, ty = t >> 4, tx = t & 15;
  float acc[8][8];
  #pragma unroll
  for (int jo = 0; jo < 8; ++jo)
    #pragma unroll
    for (int ji = 0; ji < 8; ++ji) acc[jo][ji] = 0.f;
  for (int c0 = 0; c0 < Cin; c0 += 32) {
    __syncthreads();
    for (int e = t; e < 1024; e += 256) {
      int o = (e & 15) | ((e >> 7) << 4), cq = (e >> 4) & 7;
      float4 w4 = *(const float4*)&W[(size_t)(o0 + o) * wstride + wcoff + c0 + cq * 4];
      Ws[cq * 4 + 0][o] = w4.x; Ws[cq * 4 + 1][o] = w4.y; Ws[cq * 4 + 2][o] = w4.z; Ws[cq * 4 + 3][o] = w4.w;
    }
    for (int e = t; e < 1024; e += 256) {
      int c = e >> 5, nq = e & 31;
      float4 v = *(const float4*)&in[((size_t)b * Cin + c0 + c) * N + n0 + nq * 4];
      if (inms) {
        float m = inms[c0 + c];
        float sd = sqrtf(inms[Cin + c0 + c] + BNEPS);
        v.x = (v.x - m) / sd; v.x = v.x > 0.f ? v.x : 0.f;
        v.y = (v.y - m) / sd; v.y = v.y > 0.f ? v.y : 0.f;
        v.z = (v.z - m) / sd; v.z = v.z > 0.f ? v.z : 0.f;
        v.w = (v.w - m) / sd; v.w = v.w > 0.f ? v.w : 0.f;
      }
      *(float4*)&vs[c][nq * 4] = v;
    }
    __syncthreads();
    #pragma unroll 4
    for (int c = 0; c < 32; ++c) {
      float4 w0 = *(const float4*)&Ws[c][ty * 4];
      float4 w1 = *(const float4*)&Ws[c][64 + ty * 4];
      float4 v0 = *(const float4*)&vs[c][tx * 4];
      float4 v1 = *(const float4*)&vs[c][64 + tx * 4];
      float wv[8] = {w0.x, w0.y, w0.z, w0.w, w1.x, w1.y, w1.z, w1.w};
      float vv[8] = {v0.x, v0.y, v0.z, v0.w, v1.x, v1.y, v1.z, v1.w};
      #pragma unroll
      for (int jo = 0; jo < 8; ++jo)
        #pragma unroll
        for (int ji = 0; ji < 8; ++ji) acc[jo][ji] = fmaf(wv[jo], vv[ji], acc[jo][ji]);
    }
  }
  #pragma unroll
  for (int jo = 0; jo < 8; ++jo) {
    int o2 = o0 + ty * 4 + (jo & 3) + (jo >> 2) * 64;
    float add = bias[o2] + (extra ? extra[(size_t)b * Cout + o2] : 0.f);
    float w[8];
    #pragma unroll
    for (int ji = 0; ji < 8; ++ji) w[ji] = acc[jo][ji] + add;
    float4 a0 = make_float4(w[0], w[1], w[2], w[3]);
    float4 a1 = make_float4(w[4], w[5], w[6], w[7]);
    *(float4*)&out[((size_t)b * Cout + o2) * N + n0 + tx * 4] = a0;
    *(float4*)&out[((size_t)b * Cout + o2) * N + n0 + 64 + tx * 4] = a1;
    if (ps) {
      double s = 0, s2 = 0;
      #pragma unroll
      for (int ji = 0; ji < 8; ++ji) { double dv = (double)w[ji]; s += dv; s2 = fma(dv, dv, s2); }
      #pragma unroll
      for (int off = 1; off < 16; off <<= 1) {
        s += __shfl_xor(s, off);
        s2 += __shfl_xor(s2, off);
      }
      if (tx == 0) {
        ps[(size_t)o2 * 128 + part] = (float)s;
        ps2[(size_t)o2 * 128 + part] = (float)s2;
      }
    }
  }
}

// Wc3: stages h with fused BN+ReLU (ms: 256-channel mean/var)
__global__ __launch_bounds__(256) void wc3_kernel(const float* __restrict__ h, const float* __restrict__ Wc3,
                                                  const float* __restrict__ bc3, const float* __restrict__ ms,
                                                  float* __restrict__ out) {
  __shared__ float Ws[13][257];
  __shared__ float msm[256], msd[256];
  int bx = blockIdx.x;  // B*8
  int b = bx >> 3, n0 = (bx & 7) * 256;
  int t = threadIdx.x;
  for (int e = t; e < 13 * 256; e += 256) { int o = e >> 8, c = e & 255; Ws[o][c] = Wc3[o * 256 + c]; }
  if (t < 256) { msm[t] = ms[t]; msd[t] = sqrtf(ms[256 + t] + BNEPS); }
  __syncthreads();
  float s[13];
  #pragma unroll
  for (int o = 0; o < 13; ++o) s[o] = 0.f;
  const float* hb = h + (size_t)b * 256 * N + n0 + t;
  #pragma unroll 4
  for (int c = 0; c < 256; ++c) {
    float hv = (hb[(size_t)c * N] - msm[c]) / msd[c];
    hv = hv > 0.f ? hv : 0.f;
    #pragma unroll
    for (int o = 0; o < 13; ++o) s[o] = fmaf(Ws[o][c], hv, s[o]);
  }
  #pragma unroll
  for (int o = 0; o < 13; ++o) out[((size_t)b * 13 + o) * N + n0 + t] = s[o] + bc3[o];
}

__global__ void init_kernel(float* __restrict__ premax) {
  int i = blockIdx.x * 256 + threadIdx.x;
  if (i < 8192) premax[i] = -3.402823466e38f;
}

}  // namespace

extern "C" void kernel_launch(void* const* d_in, const int* in_sizes, int n_in,
                              void* d_out, int out_size, void* d_ws, size_t ws_size,
                              hipStream_t stream) {
  const float* x   = (const float*)d_in[0];
  const float* We1 = (const float*)d_in[1];
  const float* be1 = (const float*)d_in[2];
  const float* We2 = (const float*)d_in[3];
  const float* be2 = (const float*)d_in[4];
  const float* Wq  = (const float*)d_in[5];
  const float* Wk  = (const float*)d_in[6];
  const float* Wt  = (const float*)d_in[7];
  const float* bt  = (const float*)d_in[8];
  const float* Wf  = (const float*)d_in[9];
  const float* bf  = (const float*)d_in[10];
  const float* Wc1 = (const float*)d_in[11];
  const float* bc1 = (const float*)d_in[12];
  const float* Wc2 = (const float*)d_in[13];
  const float* bc2 = (const float*)d_in[14];
  const float* Wc3 = (const float*)d_in[15];
  const float* bc3 = (const float*)d_in[16];
  float* out = (float*)d_out;

  char* w = (char*)d_ws;
  size_t off = 0;
  auto take = [&](size_t nbytes) { void* p = w + off; off += (nbytes + 255) & ~(size_t)255; return p; };
  int*    idx1   = (int*)   take((size_t)B * N * KNN * 4);
  int*    idx2   = (int*)   take((size_t)B * N * KNN * 4);
  float*  f1     = (float*) take((size_t)B * 64 * N * 4);
  float*  f2     = (float*) take((size_t)B * 64 * N * 4);
  float*  f1t    = (float*) take((size_t)B * N * 64 * 4);
  double* xx2d   = (double*)take((size_t)B * N * 8);
  double* epart  = (double*)take((size_t)B * N * 128 * 8);
  float*  emax   = (float*) take((size_t)B * 64 * N * 4);
  float*  ems    = (float*) take(128 * 4);
  float*  feat   = (float*) take((size_t)B * 128 * N * 4);
  float*  cat    = (float*) take((size_t)B * 512 * N * 4);
  float*  xq     = (float*) take((size_t)B * N * 32 * 4);
  float*  xk     = (float*) take((size_t)B * 32 * N * 4);
  float*  rowmax = (float*) take((size_t)B * N * 4);
  float*  rowsum = (float*) take((size_t)B * N * 4);
  float*  rowpart= (float*) take((size_t)4 * B * N * 2 * 4);
  float*  ubuf   = (float*) take((size_t)B * 256 * N * 4);  // SA: tpre (2nd half) ; later: pre2
  float*  tpre   = ubuf + (size_t)B * 128 * N;
  float*  pre2   = ubuf;
  float*  bnstats= (float*) take(2048 * 4);
  float*  fps    = (float*) take((size_t)1024 * 256 * 4);
  float*  fps2   = (float*) take((size_t)1024 * 256 * 4);
  float*  wtps   = (float*) take((size_t)128 * 256 * 4);
  float*  wtps2  = (float*) take((size_t)128 * 256 * 4);
  float*  mgps   = (float*) take((size_t)512 * 128 * 4);
  float*  mgps2  = (float*) take((size_t)512 * 128 * 4);
  float*  premax = (float*) take((size_t)B * 1024 * 4);
  float*  gbuf   = (float*) take((size_t)B * 1024 * 4);
  float*  gproj  = (float*) take((size_t)B * 512 * 4);
  float*  pre1   = (float*) take((size_t)B * 512 * N * 4);
  // aliases (phase-disjoint): Yp (SA partial Y, 4*B*128*N) <-> pre1 ; cspart (4*B*N) <-> fps
  float*  Yp     = pre1;
  float*  cspart = fps;
  (void)ws_size; (void)in_sizes; (void)n_in; (void)out_size;

  init_kernel<<<32, 256, 0, stream>>>(premax);

  // EdgeConv block 1
  knn1_kernel<<<B * N, 256, 0, stream>>>(x, idx1);
  edge1_kernel<<<B * N, 256, 0, stream>>>(x, idx1, We1, be1, emax, epart);
  edge_stats_kernel<<<64, 256, 0, stream>>>(epart, ems);
  edge_finish_kernel<<<B * 64 * N / 256, 256, 0, stream>>>(emax, ems, f1, f1t);

  // EdgeConv block 2
  xx2_kernel<<<B * N / 256, 256, 0, stream>>>(f1, xx2d);
  knn2_kernel<<<B * N / 4, 256, 0, stream>>>(f1, f1t, xx2d, idx2);
  edge2_kernel<<<B * 512, 256, 0, stream>>>(f1t, idx2, We2, be2, emax, epart);
  edge_stats_kernel<<<64, 256, 0, stream>>>(epart, ems);
  edge_finish_kernel<<<B * 64 * N / 256, 256, 0, stream>>>(emax, ems, f2, nullptr);
  concat_feat_kernel<<<B * 128 * N / 256, 256, 0, stream>>>(f1, f2, feat);

  // 4 SA layers
  for (int lay = 0; lay < 4; ++lay) {
    const float* xs = lay ? cat : feat;
    int bstride = lay ? 512 * N : 128 * N;
    int coff = lay ? (lay - 1) * 128 : 0;
    sa_qk_kernel<<<B * 32, 256, 0, stream>>>(xs, bstride, coff, Wq + lay * 32 * 128, Wk + lay * 32 * 128, xq, xk);
    sa_rowstats_kernel<<<512, 256, 0, stream>>>(xq, xk, rowpart);
    rowstats_merge_kernel<<<B * N / 256, 256, 0, stream>>>(rowpart, rowmax, rowsum);
    sa_attny_kernel<<<B * 32 * 4, 256, 0, stream>>>(xs, bstride, coff, xq, xk, rowmax, rowsum, Yp, cspart);
    sa_wt_kernel<<<B * 32, 256, 0, stream>>>(xs, bstride, coff, Yp, cspart, Wt + lay * 128 * 128, bt + lay * 128,
                                             tpre, wtps, wtps2);
    stats_from_parts_kernel<<<128, 256, 0, stream>>>(wtps, wtps2, bnstats, 128, 256);
    sa_out_kernel<<<B * 128 * N / 256, 256, 0, stream>>>(tpre, bnstats, xs, bstride, coff, cat, lay);
  }

  // fuse -> g
  fuse_kernel<<<B * 8 * 16, 256, 0, stream>>>(cat, Wf, bf, fps, fps2, premax);
  stats_from_parts_kernel<<<1024, 256, 0, stream>>>(fps, fps2, bnstats, 1024, 128);
  g_kernel<<<B * 1024 / 256, 256, 0, stream>>>(premax, bnstats, gbuf);

  // Wc1 (split: g-projection + cat GEMM) with fused BN-partials
  gproj_kernel<<<B * 512 / 256, 256, 0, stream>>>(Wc1, gbuf, gproj);
  mlp_gemm_kernel<<<B * 4 * 16, 256, 0, stream>>>(cat, 512, Wc1, 1536, 1024, bc1, gproj, 512, pre1,
                                                  nullptr, mgps, mgps2);
  stats_from_parts_kernel<<<512, 256, 0, stream>>>(mgps, mgps2, bnstats, 512, 128);

  // Wc2: input BN+ReLU fused into staging; emits its own BN partials
  mlp_gemm_kernel<<<B * 2 * 16, 256, 0, stream>>>(pre1, 512, Wc2, 512, 0, bc2, nullptr, 256, pre2,
                                                  bnstats, mgps, mgps2);
  stats_from_parts_kernel<<<256, 256, 0, stream>>>(mgps, mgps2, bnstats, 256, 128);

  // Wc3 with fused input BN+ReLU
  wc3_kernel<<<B * 8, 256, 0, stream>>>(pre2, Wc3, bc3, bnstats, out);
}